// Round 12
// baseline (1505.922 us; speedup 1.0000x reference)
//
#include <hip/hip_runtime.h>
#include <hip/hip_bf16.h>

#define HF 128

typedef unsigned int uint32;
typedef unsigned short ushort16;
typedef float f32x4 __attribute__((ext_vector_type(4)));
typedef __bf16 bf16x8 __attribute__((ext_vector_type(8)));

// ---- bf16 helpers ----
__device__ __forceinline__ float bflo(uint32 u) { return __uint_as_float(u << 16); }
__device__ __forceinline__ float bfhi(uint32 u) { return __uint_as_float(u & 0xffff0000u); }
__device__ __forceinline__ ushort16 f2bf(float f) {
  uint32 u = __float_as_uint(f);
  return (ushort16)((u + 0x7fffu + ((u >> 16) & 1u)) >> 16);
}
__device__ __forceinline__ uint32 pack2(float lo, float hi) {
  return (uint32)f2bf(lo) | ((uint32)f2bf(hi) << 16);
}

// ---------------------------------------------------------------------------
__global__ void diag_k(float* __restrict__ out, int n, float val) {
  int i = blockIdx.x * 256 + threadIdx.x;
  if (i < n) out[i] = val;
}

// fused setup: conv_a, conv_b, initcs, pool-zero, rp-zero, dummy-row zero
__global__ __launch_bounds__(256) void setup_k(
    const float* __restrict__ xa, const float* __restrict__ xb,
    uint32* __restrict__ XA0, uint32* __restrict__ XA1,
    uint32* __restrict__ XB0, uint32* __restrict__ XB1,
    int n4a, int n4b,
    int* __restrict__ cs, size_t capA, size_t capB, size_t capC, int vA, int vB,
    float* __restrict__ pool, int poolN4,
    int* __restrict__ rpz, int rpN4,
    size_t dummyA, size_t dummyB,
    int CA, int CB, int CI, int PZ, int RZ) {
  int b = blockIdx.x, t = threadIdx.x;
  if (b < CA) {
    int i = b * 256 + t;
    if (i < n4a) {
      float4 v = ((const float4*)xa)[i];
      uint2 p; p.x = pack2(v.x, v.y); p.y = pack2(v.z, v.w);
      ((uint2*)XA0)[i] = p;
    }
    return;
  }
  b -= CA;
  if (b < CB) {
    int i = b * 256 + t;
    if (i < n4b) {
      float4 v = ((const float4*)xb)[i];
      uint2 p; p.x = pack2(v.x, v.y); p.y = pack2(v.z, v.w);
      ((uint2*)XB0)[i] = p;
    }
    return;
  }
  b -= CB;
  if (b < CI) {
    size_t i = ((size_t)b * 256 + t) * 4;
    size_t tot = capA + capB + capC;
    if (i < tot) {
      int v = (i < capA + capB) ? vA : vB;
      int4 w = make_int4(v, v, v, v);
      *(int4*)&cs[i] = w;
    }
    return;
  }
  b -= CI;
  if (b < PZ) {
    int i = b * 256 + t;
    if (i < poolN4) ((float4*)pool)[i] = make_float4(0.f, 0.f, 0.f, 0.f);
    return;
  }
  b -= PZ;
  if (b < RZ) {
    int i = b * 256 + t;
    if (i < rpN4) ((int4*)rpz)[i] = make_int4(0, 0, 0, 0);
    return;
  }
  if (t < 64) XA0[dummyA + t] = 0;
  else if (t < 128) XA1[dummyA + (t - 64)] = 0;
  else if (t < 192) XB0[dummyB + (t - 128)] = 0;
  else XB1[dummyB + (t - 192)] = 0;
}

// ---------------------------------------------------------------------------
// CSR build: fused count (3 types) -> padded hierarchical scan -> fill
__global__ void count3_k(const int* __restrict__ eA, int EA, int* __restrict__ rA,
                         const int* __restrict__ eB, int EB, int* __restrict__ rB,
                         const int* __restrict__ eC, int EC, int* __restrict__ rC,
                         int B0, int B1) {
  int b = blockIdx.x;
  const int* ei; int E; int* rp;
  if (b < B0)            { ei = eA; E = EA; rp = rA; }
  else if (b < B0 + B1)  { ei = eB; E = EB; rp = rB; b -= B0; }
  else                   { ei = eC; E = EC; rp = rC; b -= B0 + B1; }
  int e = b * 256 + threadIdx.x;
  if (e < E) atomicAdd(&rp[ei[E + e]], 1);
}

__device__ __forceinline__ int pad4(int c) { return (c + 3) & ~3; }

__device__ __forceinline__ void scan1_body(const int* __restrict__ rp, int N,
                                           int* __restrict__ bsum, int b, int t) {
  int i = b * 1024 + t * 4;
  int s = 0;
  if (i + 3 < N) {
    int4 v = *(const int4*)&rp[i];
    s = pad4(v.x) + pad4(v.y) + pad4(v.z) + pad4(v.w);
  } else {
    for (int j = 0; j < 4; ++j) if (i + j < N) s += pad4(rp[i + j]);
  }
  __shared__ int sd[256];
  sd[t] = s;
  __syncthreads();
  for (int o = 128; o > 0; o >>= 1) {
    if (t < o) sd[t] += sd[t + o];
    __syncthreads();
  }
  if (t == 0) bsum[b] = sd[0];
}

__global__ __launch_bounds__(256) void scan1x3_k(
    const int* __restrict__ rA, int NA, int* __restrict__ bA,
    const int* __restrict__ rB, int NB, int* __restrict__ bB,
    const int* __restrict__ rC, int NC, int* __restrict__ bC, int nbA, int nbB) {
  int b = blockIdx.x;
  if (b < nbA)            scan1_body(rA, NA, bA, b, threadIdx.x);
  else if (b < nbA + nbB) scan1_body(rB, NB, bB, b - nbA, threadIdx.x);
  else                    scan1_body(rC, NC, bC, b - nbA - nbB, threadIdx.x);
}

__global__ __launch_bounds__(1024) void scan2x3_k(int* __restrict__ bA, int nbA,
                                                  int* __restrict__ bB, int nbB,
                                                  int* __restrict__ bC, int nbC) {
  int* bsum = (blockIdx.x == 0) ? bA : (blockIdx.x == 1) ? bB : bC;
  int nb    = (blockIdx.x == 0) ? nbA : (blockIdx.x == 1) ? nbB : nbC;
  __shared__ int sd[1024];
  int t = threadIdx.x;
  int v = (t < nb) ? bsum[t] : 0;
  sd[t] = v;
  __syncthreads();
  for (int o = 1; o < 1024; o <<= 1) {
    int x = (t >= o) ? sd[t - o] : 0;
    __syncthreads();
    sd[t] += x;
    __syncthreads();
  }
  if (t < nb) bsum[t] = sd[t] - v;
}

__device__ __forceinline__ void scan3_body(int* __restrict__ rp, int* __restrict__ cur,
                                           int* __restrict__ deg,
                                           const int* __restrict__ bsum, int N,
                                           int b, int t) {
  int i = b * 1024 + t * 4;
  int c[4];
  #pragma unroll
  for (int j = 0; j < 4; ++j) c[j] = (i + j < N) ? rp[i + j] : 0;
  int tsum = pad4(c[0]) + pad4(c[1]) + pad4(c[2]) + pad4(c[3]);
  __shared__ int sd[256];
  sd[t] = tsum;
  __syncthreads();
  for (int o = 1; o < 256; o <<= 1) {
    int x = (t >= o) ? sd[t - o] : 0;
    __syncthreads();
    sd[t] += x;
    __syncthreads();
  }
  int off = bsum[b] + sd[t] - tsum;
  int p = off;
  #pragma unroll
  for (int j = 0; j < 4; ++j) {
    if (i + j < N) { rp[i + j] = p; cur[i + j] = p; deg[i + j] = c[j]; }
    p += pad4(c[j]);
  }
  if (i < N && N <= i + 4) rp[N] = off + tsum;
}

__global__ __launch_bounds__(256) void scan3x3_k(
    int* __restrict__ rA, int* __restrict__ cA, int* __restrict__ dA,
    const int* __restrict__ bA, int NA,
    int* __restrict__ rB, int* __restrict__ cB, int* __restrict__ dB,
    const int* __restrict__ bB, int NB,
    int* __restrict__ rC, int* __restrict__ cC, int* __restrict__ dC,
    const int* __restrict__ bC, int NC,
    int nbA, int nbB) {
  int b = blockIdx.x;
  if (b < nbA)            scan3_body(rA, cA, dA, bA, NA, b, threadIdx.x);
  else if (b < nbA + nbB) scan3_body(rB, cB, dB, bB, NB, b - nbA, threadIdx.x);
  else                    scan3_body(rC, cC, dC, bC, NC, b - nbA - nbB, threadIdx.x);
}

#define FILL_P 4
__global__ __launch_bounds__(256) void fill3p_k(
    const int* __restrict__ eA, int EA, int* __restrict__ cuA, int* __restrict__ csA,
    const int* __restrict__ eB, int EB, int* __restrict__ cuB, int* __restrict__ csB,
    const int* __restrict__ eC, int EC, int* __restrict__ cuC, int* __restrict__ csC,
    int NA, int NBn, int B0, int B1, int Btot) {
  int pass = blockIdx.x / Btot;
  int b = blockIdx.x % Btot;
  const int* ei; int E; int* cur; int* cs; int N;
  if (b < B0)           { ei = eA; E = EA; cur = cuA; cs = csA; N = NA; }
  else if (b < B0 + B1) { ei = eB; E = EB; cur = cuB; cs = csB; N = NBn; b -= B0; }
  else                  { ei = eC; E = EC; cur = cuC; cs = csC; N = NA; b -= B0 + B1; }
  int e = b * 256 + threadIdx.x;
  if (e >= E) return;
  int dst = ei[E + e];
  int lo = (int)(((long long)pass * N) / FILL_P);
  int hi = (int)(((long long)(pass + 1) * N) / FILL_P);
  if (dst < lo || dst >= hi) return;
  int pos = atomicAdd(&cur[dst], 1);
  cs[pos] = ei[e];
}

// ---------------------------------------------------------------------------
// per-layer prep: BN finalize + weight pack + u-vectors + zero next stats.
__global__ __launch_bounds__(128) void prep2_k(
    const float* __restrict__ Wrel_l, const float* __restrict__ Wroot_l,
    const float* __restrict__ brel_l,
    const float* __restrict__ gamma, const float* __restrict__ beta,
    const float* __restrict__ statsPrev, float* __restrict__ statsNext,
    float nA, float nB, int first,
    ushort16* __restrict__ BWa, ushort16* __restrict__ BWb,
    float* __restrict__ uvec) {
  __shared__ float red[128];
  int n = blockIdx.x, k = threadIdx.x;
  float scA, shA, scB, shB;
  if (first) {
    scA = 1.f; shA = 0.f; scB = 1.f; shB = 0.f;
  } else {
    float sA = 0.f, qA = 0.f, sB = 0.f, qB = 0.f;
    for (int st = 0; st < 64; ++st) {
      sA += statsPrev[st * 128 + k];
      qA += statsPrev[8192 + st * 128 + k];
      sB += statsPrev[16384 + st * 128 + k];
      qB += statsPrev[24576 + st * 128 + k];
    }
    float mA = sA / nA, vA = qA / nA - mA * mA;
    float rA = rsqrtf(vA + 1e-5f);
    scA = gamma[k] * rA; shA = beta[k] - mA * scA;
    float mB = sB / nB, vB = qB / nB - mB * mB;
    float rB = rsqrtf(vB + 1e-5f);
    scB = gamma[128 + k] * rB; shB = beta[128 + k] - mB * scB;
  }
  if (n < 64) {
    float4 z = make_float4(0.f, 0.f, 0.f, 0.f);
    *(float4*)&statsNext[n * 512 + k * 4] = z;
  }
  float w0  = Wrel_l[n * HF + k];
  float w1  = Wrel_l[16384 + n * HF + k];
  float w2  = Wrel_l[32768 + n * HF + k];
  float wr1 = Wroot_l[16384 + n * HF + k];
  float wrc = Wroot_l[n * HF + k] + Wroot_l[32768 + n * HF + k];

  int ksl = k >> 5;
  int lane = (n & 15) + (((k >> 3) & 3) << 4);
  int j = k & 7;
  int nt = n >> 4;
  auto put = [&](ushort16* B, int ksb, float v) {
    B[((size_t)((ksb + ksl) * 8 + nt) * 64 + lane) * 8 + j] = f2bf(v);
  };
  put(BWa, 0, scA * w0);
  put(BWa, 4, scB * w2);
  put(BWa, 8, scA * wrc);
  put(BWb, 0, scA * w1);
  put(BWb, 4, scB * wr1);

  auto reduce = [&](float v) -> float {
    red[k] = v;
    __syncthreads();
    for (int s = 64; s > 0; s >>= 1) {
      if (k < s) red[k] += red[k + s];
      __syncthreads();
    }
    float r = red[0];
    __syncthreads();
    return r;
  };
  float r0 = reduce(shA * w0);    // uaa
  float r1 = reduce(shB * w2);    // uba
  float r2 = reduce(shA * w1);    // uab
  float r3 = reduce(shA * wrc);   // bias_a extra
  float r4 = reduce(shB * wr1);   // bias_b extra
  if (k == 0) {
    uvec[n]       = r0;
    uvec[128 + n] = r1;
    uvec[256 + n] = r2;
    uvec[384 + n] = brel_l[n] + brel_l[256 + n] + r3;
    uvec[512 + n] = brel_l[128 + n] + r4;
  }
}

// ---------------------------------------------------------------------------
// fused gather + MFMA GEMM + epilogue body. One wave owns 16 output rows.
// Register-lean schedule: gather1 -> frag1 -> MFMA1 -> gather2 -> frag2 ->
// MFMA2 -> root (loads issued post-gather2) -> epilogue (deg loaded here).
template <bool HAS2>
__device__ __forceinline__ void gg_body(
    int blk,
    const uint32* __restrict__ Xg1, const int* __restrict__ rp1, const int* __restrict__ cs1,
    const int* __restrict__ deg1,
    const uint32* __restrict__ Xg2, const int* __restrict__ rp2, const int* __restrict__ cs2,
    const int* __restrict__ deg2,
    const uint32* Xr,
    const bf16x8* __restrict__ BW,
    const float* __restrict__ u1, const float* __restrict__ u2,
    const float* __restrict__ bias,
    uint32* out,
    float* __restrict__ statS, float* __restrict__ statQ,
    int nRows, uint32* L) {
  constexpr int KS_G = HAS2 ? 8 : 4;
  int tid = threadIdx.x, l = tid & 63, wid = tid >> 6;
  int R0 = blk * 64 + wid * 16;
  int row = l & 15, khi = l >> 4;
  int myRow = R0 + row;
  bool okRow = myRow < nRows;
  int rowIdx = okRow ? myRow : nRows;

  // prologue: row ranges + first index quad of tile 1
  int e0a = 0, e1a = 0;
  if (okRow) { e0a = rp1[myRow]; e1a = rp1[myRow + 1]; }
  int e0b = 0, e1b = 0;
  if constexpr (HAS2) { if (okRow) { e0b = rp2[myRow]; e1b = rp2[myRow + 1]; } }
  int4 q1 = make_int4(0, 0, 0, 0);
  if (e0a < e1a) q1 = *(const int4*)&cs1[e0a];

  float lo[16], hi[16];
  auto addv = [&](int base, uint4 v) {
    hi[base + 0] += __uint_as_float(v.x); lo[base + 0] += __uint_as_float(v.x << 16);
    hi[base + 1] += __uint_as_float(v.y); lo[base + 1] += __uint_as_float(v.y << 16);
    hi[base + 2] += __uint_as_float(v.z); lo[base + 2] += __uint_as_float(v.z << 16);
    hi[base + 3] += __uint_as_float(v.w); lo[base + 3] += __uint_as_float(v.w << 16);
  };
  auto run_tile = [&](const uint32* __restrict__ Xg, const int* __restrict__ cs,
                      int e0, int e1, int4 qinit) {
    #pragma unroll
    for (int i = 0; i < 16; ++i) { lo[i] = 0.f; hi[i] = 0.f; }
    if (e0 >= e1) return;
    int e = e0;
    int4 q = qinit;
    for (;;) {
      const uint32* p0 = &Xg[(size_t)q.x * 64 + khi * 4];
      const uint32* p1 = &Xg[(size_t)q.y * 64 + khi * 4];
      const uint32* p2 = &Xg[(size_t)q.z * 64 + khi * 4];
      const uint32* p3 = &Xg[(size_t)q.w * 64 + khi * 4];
      uint4 a0 = *(const uint4*)&p0[0];
      uint4 a1 = *(const uint4*)&p0[16];
      uint4 a2 = *(const uint4*)&p0[32];
      uint4 a3 = *(const uint4*)&p0[48];
      uint4 b0 = *(const uint4*)&p1[0];
      uint4 b1 = *(const uint4*)&p1[16];
      uint4 b2 = *(const uint4*)&p1[32];
      uint4 b3 = *(const uint4*)&p1[48];
      uint4 c0 = *(const uint4*)&p2[0];
      uint4 c1 = *(const uint4*)&p2[16];
      uint4 c2 = *(const uint4*)&p2[32];
      uint4 c3 = *(const uint4*)&p2[48];
      uint4 d0 = *(const uint4*)&p3[0];
      uint4 d1 = *(const uint4*)&p3[16];
      uint4 d2 = *(const uint4*)&p3[32];
      uint4 d3 = *(const uint4*)&p3[48];
      int en = e + 4;
      bool more = en < e1;
      int4 qn = q;
      if (more) qn = *(const int4*)&cs[en];
      addv(0, a0); addv(4, a1); addv(8, a2); addv(12, a3);
      addv(0, b0); addv(4, b1); addv(8, b2); addv(12, b3);
      addv(0, c0); addv(4, c1); addv(8, c2); addv(12, c3);
      addv(0, d0); addv(4, d1); addv(8, d2); addv(12, d3);
      if (!more) break;
      e = en; q = qn;
    }
  };
  auto to_frag = [&](int ks) -> bf16x8 {
    bf16x8 a;
    #pragma unroll
    for (int j = 0; j < 4; ++j) {
      a[2 * j]     = (__bf16)lo[ks * 4 + j];
      a[2 * j + 1] = (__bf16)hi[ks * 4 + j];
    }
    return a;
  };

  f32x4 acc[8] = {};
  const bf16x8* Bl = BW + l;

  // ---- tile 1: gather -> frags -> MFMA (frees lo/hi before tile 2) ----
  run_tile(Xg1, cs1, e0a, e1a, q1);
  {
    bf16x8 af[4];
    #pragma unroll
    for (int ks = 0; ks < 4; ++ks) af[ks] = to_frag(ks);
    // issue tile-2's first index quad under MFMA1
    int4 q2 = make_int4(0, 0, 0, 0);
    if constexpr (HAS2) { if (e0b < e1b) q2 = *(const int4*)&cs2[e0b]; }
    #pragma unroll
    for (int ks = 0; ks < 4; ++ks) {
      #pragma unroll
      for (int nt = 0; nt < 8; ++nt) {
        bf16x8 b = Bl[(size_t)(ks * 8 + nt) * 64];
        acc[nt] = __builtin_amdgcn_mfma_f32_16x16x32_bf16(af[ks], b, acc[nt], 0, 0, 0);
      }
    }
    if constexpr (HAS2) {
      // ---- tile 2 ----
      run_tile(Xg2, cs2, e0b, e1b, q2);
      bf16x8 af2[4];
      #pragma unroll
      for (int ks = 0; ks < 4; ++ks) af2[ks] = to_frag(ks);
      #pragma unroll
      for (int ks = 0; ks < 4; ++ks) {
        #pragma unroll
        for (int nt = 0; nt < 8; ++nt) {
          bf16x8 b = Bl[(size_t)((4 + ks) * 8 + nt) * 64];
          acc[nt] = __builtin_amdgcn_mfma_f32_16x16x32_bf16(af2[ks], b, acc[nt], 0, 0, 0);
        }
      }
    }
  }
  // ---- root k-steps ----
  {
    bf16x8 rt[4];
    #pragma unroll
    for (int ks = 0; ks < 4; ++ks)
      rt[ks] = *(const bf16x8*)&Xr[(size_t)rowIdx * 64 + (ks * 4 + khi) * 4];
    #pragma unroll
    for (int ks = 0; ks < 4; ++ks) {
      #pragma unroll
      for (int nt = 0; nt < 8; ++nt) {
        bf16x8 b = Bl[(size_t)((KS_G + ks) * 8 + nt) * 64];
        acc[nt] = __builtin_amdgcn_mfma_f32_16x16x32_bf16(rt[ks], b, acc[nt], 0, 0, 0);
      }
    }
  }

  // ---- epilogue (deg loaded here, freed from whole-kernel liveness) ----
  int rl0 = khi * 4;
  float dg1[4] = {0.f, 0.f, 0.f, 0.f}, dg2[4] = {0.f, 0.f, 0.f, 0.f};
  #pragma unroll
  for (int j = 0; j < 4; ++j) {
    int r = R0 + rl0 + j;
    if (r < nRows) {
      dg1[j] = (float)deg1[r];
      if constexpr (HAS2) dg2[j] = (float)deg2[r];
    }
  }
  ushort16* P = (ushort16*)L;   // [16 rows][stride 136 ushorts]
  int c0 = l & 15;
  float ps[8], pq[8];
  #pragma unroll
  for (int nt = 0; nt < 8; ++nt) {
    int col = nt * 16 + c0;
    float bc = bias[col];
    float u1c = u1[col];
    float u2c = HAS2 ? u2[col] : 0.f;
    float s = 0.f, q = 0.f;
    #pragma unroll
    for (int j = 0; j < 4; ++j) {
      float v = acc[nt][j] + bc + dg1[j] * u1c;
      if constexpr (HAS2) v += dg2[j] * u2c;
      v = fmaxf(v, 0.f);
      if (R0 + rl0 + j < nRows) { s += v; q += v * v; }
      P[(rl0 + j) * 136 + col] = f2bf(v);
    }
    ps[nt] = s; pq[nt] = q;
  }

  #pragma unroll
  for (int rr = 0; rr < 4; ++rr) {
    int rloc = rr * 4 + khi;
    int grow = R0 + rloc;
    if (grow < nRows) {
      uint4 v = *(const uint4*)&P[rloc * 136 + c0 * 8];
      *(uint4*)&out[(size_t)grow * 64 + c0 * 4] = v;
    }
  }

  #pragma unroll
  for (int nt = 0; nt < 8; ++nt) {
    ps[nt] += __shfl_xor(ps[nt], 16); ps[nt] += __shfl_xor(ps[nt], 32);
    pq[nt] += __shfl_xor(pq[nt], 16); pq[nt] += __shfl_xor(pq[nt], 32);
  }
  if (l < 16) {
    float* S = statS + (size_t)(blk & 63) * 128;
    float* Q = statQ + (size_t)(blk & 63) * 128;
    #pragma unroll
    for (int nt = 0; nt < 8; ++nt) {
      unsafeAtomicAdd(&S[nt * 16 + l], ps[nt]);
      unsafeAtomicAdd(&Q[nt * 16 + l], pq[nt]);
    }
  }
}

// merged per-layer kernel: blocks [0,nbA) = type a, [nbA, nbA+nbB) = type b
__global__ __launch_bounds__(256, 5) void gg2_k(
    const uint32* __restrict__ XAc, const uint32* __restrict__ XBc,
    const int* __restrict__ rp_aa, const int* __restrict__ cs_aa, const int* __restrict__ deg_aa,
    const int* __restrict__ rp_ba, const int* __restrict__ cs_ba, const int* __restrict__ deg_ba,
    const int* __restrict__ rp_ab, const int* __restrict__ cs_ab, const int* __restrict__ deg_ab,
    const bf16x8* __restrict__ BWa, const bf16x8* __restrict__ BWb,
    const float* __restrict__ uvec,
    uint32* outA, uint32* outB,
    float* __restrict__ stats,
    int Na, int Nb, int nbA) {
  __shared__ uint32 lds[4][1088];
  uint32* L = &lds[threadIdx.x >> 6][0];
  int b = blockIdx.x;
  if (b < nbA) {
    gg_body<true>(b, XAc, rp_aa, cs_aa, deg_aa, XBc, rp_ba, cs_ba, deg_ba,
                  XAc, BWa, uvec, uvec + 128, uvec + 384, outA,
                  stats, stats + 8192, Na, L);
  } else {
    gg_body<false>(b - nbA, XAc, rp_ab, cs_ab, deg_ab,
                   nullptr, nullptr, nullptr, nullptr,
                   XBc, BWb, uvec + 256, nullptr, uvec + 512, outB,
                   stats + 16384, stats + 24576, Nb, L);
  }
}

// ---------------------------------------------------------------------------
__global__ void bn_fin_k(const float* __restrict__ stats, const float* __restrict__ gamma,
                         const float* __restrict__ beta, float* __restrict__ ss,
                         float nA, float nB) {
  int t = threadIdx.x;
  if (t >= 256) return;
  int type = t >> 7, f = t & 127;
  const float* S = stats + (size_t)type * 16384;
  const float* Q = S + 8192;
  float s = 0.f, q = 0.f;
  for (int st = 0; st < 64; ++st) { s += S[st * 128 + f]; q += Q[st * 128 + f]; }
  float nN = type ? nB : nA;
  float mean = s / nN;
  float var = q / nN - mean * mean;
  float rstd = rsqrtf(var + 1e-5f);
  float sc = gamma[type * HF + f] * rstd;
  float sh = beta[type * HF + f] - mean * sc;
  ss[type * 256 + f] = sc;
  ss[type * 256 + 128 + f] = sh;
}

// ---------------------------------------------------------------------------
__global__ __launch_bounds__(256) void pool_k(const uint32* __restrict__ x,
                                              const int* __restrict__ batch,
                                              const float* __restrict__ scale,
                                              const float* __restrict__ shift,
                                              float* __restrict__ pool, int nN) {
  int f2 = threadIdx.x & 31;
  int sub = threadIdx.x >> 5;
  int start = blockIdx.x * 1024;
  int end = min(start + 1024, nN);
  float4 sc = *(const float4*)&scale[f2 * 4];
  float4 sh = *(const float4*)&shift[f2 * 4];
  float a0 = 0.f, a1 = 0.f, a2 = 0.f, a3 = 0.f, cnt = 0.f;
  int cur = -1;
  for (int n = start + sub; n < end; n += 8) {
    int g = batch[n];
    if (g != cur) {
      if (cur >= 0) {
        float* bp = &pool[(size_t)cur * HF + f2 * 4];
        unsafeAtomicAdd(bp + 0, sc.x * a0 + cnt * sh.x);
        unsafeAtomicAdd(bp + 1, sc.y * a1 + cnt * sh.y);
        unsafeAtomicAdd(bp + 2, sc.z * a2 + cnt * sh.z);
        unsafeAtomicAdd(bp + 3, sc.w * a3 + cnt * sh.w);
      }
      a0 = a1 = a2 = a3 = 0.f; cnt = 0.f; cur = g;
    }
    uint2 v = *(const uint2*)&x[(size_t)n * 64 + f2 * 2];
    a0 += bflo(v.x); a1 += bfhi(v.x); a2 += bflo(v.y); a3 += bfhi(v.y);
    cnt += 1.f;
  }
  if (cur >= 0) {
    float* bp = &pool[(size_t)cur * HF + f2 * 4];
    unsafeAtomicAdd(bp + 0, sc.x * a0 + cnt * sh.x);
    unsafeAtomicAdd(bp + 1, sc.y * a1 + cnt * sh.y);
    unsafeAtomicAdd(bp + 2, sc.z * a2 + cnt * sh.z);
    unsafeAtomicAdd(bp + 3, sc.w * a3 + cnt * sh.w);
  }
}

__device__ inline int lowerb(const int* a, int n, int v) {
  int lo = 0, hi = n;
  while (lo < hi) { int m = (lo + hi) >> 1; if (a[m] < v) lo = m + 1; else hi = m; }
  return lo;
}

__global__ void final_k(const float* __restrict__ pool,
                        const int* __restrict__ ba, int nA,
                        const int* __restrict__ bb, int nB,
                        const float* __restrict__ linW, const float* __restrict__ linb,
                        float* __restrict__ out, int Cn) {
  int g = blockIdx.x;
  int lane = threadIdx.x;
  int c = (lowerb(ba, nA, g + 1) - lowerb(ba, nA, g)) +
          (lowerb(bb, nB, g + 1) - lowerb(bb, nB, g));
  float inv = 1.f / fmaxf((float)c, 1.f);
  float p0 = pool[(size_t)g * HF + lane] * inv;
  float p1 = pool[(size_t)g * HF + 64 + lane] * inv;
  for (int cc = 0; cc < Cn; ++cc) {
    float t = p0 * linW[cc * HF + lane] + p1 * linW[cc * HF + 64 + lane];
    for (int off = 32; off > 0; off >>= 1) t += __shfl_down(t, off);
    if (lane == 0) out[g * Cn + cc] = t + linb[cc];
  }
}

// ---------------------------------------------------------------------------
extern "C" void kernel_launch(void* const* d_in, const int* in_sizes, int n_in,
                              void* d_out, int out_size, void* d_ws, size_t ws_size,
                              hipStream_t stream) {
  const float* x_a   = (const float*)d_in[0];
  const float* x_b   = (const float*)d_in[1];
  const float* Wrel  = (const float*)d_in[2];
  const float* brel  = (const float*)d_in[3];
  const float* Wroot = (const float*)d_in[4];
  const float* bn_g  = (const float*)d_in[5];
  const float* bn_b  = (const float*)d_in[6];
  const float* lin_W = (const float*)d_in[7];
  const float* lin_b = (const float*)d_in[8];
  const int* ei_aa   = (const int*)d_in[9];
  const int* ei_ab   = (const int*)d_in[10];
  const int* ei_ba   = (const int*)d_in[11];
  const int* batch_a = (const int*)d_in[12];
  const int* batch_b = (const int*)d_in[13];

  int Na  = in_sizes[0] / HF;
  int Nb  = in_sizes[1] / HF;
  int Eaa = in_sizes[9] / 2;
  int Eab = in_sizes[10] / 2;
  int Eba = in_sizes[11] / 2;
  int Cn  = in_sizes[7] / HF;
  int Gn  = out_size / Cn;

  size_t NHa = (size_t)Na * HF, NHb = (size_t)Nb * HF;
  size_t capA = ((size_t)Eaa + 3 * (size_t)Na + 15) & ~(size_t)15;
  size_t capB = ((size_t)Eab + 3 * (size_t)Nb + 15) & ~(size_t)15;
  size_t capC = ((size_t)Eba + 3 * (size_t)Na + 15) & ~(size_t)15;

  char* base = (char*)d_ws;
  auto alignup = [](size_t x) { return (x + 255) & ~(size_t)255; };
  size_t off = 0;
  size_t oXA0 = off; off = alignup(off + (NHa + HF) * 2);
  size_t oXA1 = off; off = alignup(off + (NHa + HF) * 2);
  size_t oXB0 = off; off = alignup(off + (NHb + HF) * 2);
  size_t oRP  = off; off = alignup(off + ((size_t)(Na + 1) + (Nb + 1) + (Na + 1)) * 4);
  size_t oCUR = off; off = alignup(off + ((size_t)Na + Nb + Na) * 4);
  size_t oDEG = off; off = alignup(off + ((size_t)Na + Nb + Na) * 4);
  size_t oCS  = off; off = alignup(off + (capA + capB + capC) * 4);
  size_t oBWA = off; off = alignup(off + (size_t)12 * 8 * 64 * 16);
  size_t oBWB = off; off = alignup(off + (size_t)8 * 8 * 64 * 16);
  size_t oUV  = off; off = alignup(off + 5 * 128 * 4);
  size_t oSS  = off; off = alignup(off + 512 * 4);
  size_t oST  = off; off = alignup(off + 65536 * 4);
  size_t oBS  = off; off = alignup(off + 3072 * 4);
  size_t oPOOL= off; off = alignup(off + (size_t)Gn * HF * 4);
  size_t need_min = off;
  size_t oXB1 = off; off = alignup(off + (NHb + HF) * 2);
  size_t need_full = off;

  if (ws_size < need_min) {
    diag_k<<<(out_size + 255) / 256, 256, 0, stream>>>(
        (float*)d_out, out_size, (float)((double)ws_size / 1048576.0));
    return;
  }
  bool merged = ws_size >= need_full;

  uint32* XA0 = (uint32*)(base + oXA0);
  uint32* XA1 = (uint32*)(base + oXA1);
  uint32* XB0 = (uint32*)(base + oXB0);
  uint32* XB1 = merged ? (uint32*)(base + oXB1) : XB0;
  int* rp_aa = (int*)(base + oRP);
  int* rp_ab = rp_aa + (Na + 1);
  int* rp_ba = rp_ab + (Nb + 1);
  int* cur_aa = (int*)(base + oCUR);
  int* cur_ab = cur_aa + Na;
  int* cur_ba = cur_ab + Nb;
  int* deg_aa = (int*)(base + oDEG);
  int* deg_ab = deg_aa + Na;
  int* deg_ba = deg_ab + Nb;
  int* cs_aa = (int*)(base + oCS);
  int* cs_ab = cs_aa + capA;
  int* cs_ba = cs_ab + capB;
  ushort16* BWa = (ushort16*)(base + oBWA);
  ushort16* BWb = (ushort16*)(base + oBWB);
  float* uvec  = (float*)(base + oUV);
  float* ss    = (float*)(base + oSS);
  float* stats = (float*)(base + oST);
  int* bsum    = (int*)(base + oBS);
  float* pool  = (float*)(base + oPOOL);

  float* ss_a = ss;
  float* ss_b = ss + 256;

  int n4a = (int)(NHa / 4), n4b = (int)(NHb / 4);
  int CA = (n4a + 255) / 256, CB = (n4b + 255) / 256;
  size_t capTot = capA + capB + capC;
  int CI = (int)((capTot / 4 + 255) / 256);
  int poolN4 = Gn * HF / 4;
  int PZ = (poolN4 + 255) / 256;
  int rpCnt = (Na + 1) + (Nb + 1) + (Na + 1);
  int rpN4 = (rpCnt + 3) / 4;
  int RZ = (rpN4 + 255) / 256;
  setup_k<<<CA + CB + CI + PZ + RZ + 1, 256, 0, stream>>>(
      x_a, x_b, XA0, XA1, XB0, XB1, n4a, n4b,
      cs_aa, capA, capB, capC, Na, Nb,
      pool, poolN4, rp_aa, rpN4,
      NHa / 2, NHb / 2, CA, CB, CI, PZ, RZ);

  int B0 = (Eaa + 255) / 256, B1 = (Eab + 255) / 256, B2 = (Eba + 255) / 256;
  count3_k<<<B0 + B1 + B2, 256, 0, stream>>>(ei_aa, Eaa, rp_aa, ei_ab, Eab, rp_ab,
                                             ei_ba, Eba, rp_ba, B0, B1);

  int nb_a = (Na + 1023) / 1024;
  int nb_b = (Nb + 1023) / 1024;
  scan1x3_k<<<nb_a + nb_b + nb_a, 256, 0, stream>>>(
      rp_aa, Na, bsum, rp_ab, Nb, bsum + 1024, rp_ba, Na, bsum + 2048, nb_a, nb_b);
  scan2x3_k<<<3, 1024, 0, stream>>>(bsum, nb_a, bsum + 1024, nb_b, bsum + 2048, nb_a);
  scan3x3_k<<<nb_a + nb_b + nb_a, 256, 0, stream>>>(
      rp_aa, cur_aa, deg_aa, bsum, Na,
      rp_ab, cur_ab, deg_ab, bsum + 1024, Nb,
      rp_ba, cur_ba, deg_ba, bsum + 2048, Na, nb_a, nb_b);

  int Btot = B0 + B1 + B2;
  fill3p_k<<<FILL_P * Btot, 256, 0, stream>>>(ei_aa, Eaa, cur_aa, cs_aa,
                                              ei_ab, Eab, cur_ab, cs_ab,
                                              ei_ba, Eba, cur_ba, cs_ba,
                                              Na, Nb, B0, B1, Btot);

  int nbA = (Na + 63) / 64;
  int nbB = (Nb + 63) / 64;
  uint32* xa_cur = XA0;
  uint32* xa_nxt = XA1;
  uint32* xb_cur = XB0;
  uint32* xb_nxt = XB1;
  for (int l = 0; l < 3; ++l) {
    const float* Wrel_l  = Wrel  + (size_t)l * 3 * 16384;
    const float* Wroot_l = Wroot + (size_t)l * 3 * 16384;
    const float* brel_l  = brel  + (size_t)l * 3 * HF;
    float* statsCur  = stats + (size_t)(l & 1) * 32768;
    float* statsPrev = stats + (size_t)((l + 1) & 1) * 32768;

    prep2_k<<<128, 128, 0, stream>>>(Wrel_l, Wroot_l, brel_l, bn_g, bn_b,
                                     statsPrev, statsCur, (float)Na, (float)Nb,
                                     (l == 0) ? 1 : 0, BWa, BWb, uvec);

    if (merged) {
      gg2_k<<<nbA + nbB, 256, 0, stream>>>(
          xa_cur, xb_cur, rp_aa, cs_aa, deg_aa, rp_ba, cs_ba, deg_ba,
          rp_ab, cs_ab, deg_ab,
          (const bf16x8*)BWa, (const bf16x8*)BWb, uvec,
          xa_nxt, xb_nxt, statsCur, Na, Nb, nbA);
      uint32* t2 = xb_cur; xb_cur = xb_nxt; xb_nxt = t2;
    } else {
      gg2_k<<<nbA, 256, 0, stream>>>(
          xa_cur, xb_cur, rp_aa, cs_aa, deg_aa, rp_ba, cs_ba, deg_ba,
          rp_ab, cs_ab, deg_ab,
          (const bf16x8*)BWa, (const bf16x8*)BWb, uvec,
          xa_nxt, nullptr, statsCur, Na, Nb, nbA);
      gg2_k<<<nbB, 256, 0, stream>>>(
          xa_cur, xb_cur, rp_aa, cs_aa, deg_aa, rp_ba, cs_ba, deg_ba,
          rp_ab, cs_ab, deg_ab,
          (const bf16x8*)BWa, (const bf16x8*)BWb, uvec,
          nullptr, xb_cur, statsCur, Na, Nb, 0);
    }
    uint32* t = xa_cur; xa_cur = xa_nxt; xa_nxt = t;
  }

  bn_fin_k<<<1, 256, 0, stream>>>(stats, bn_g, bn_b, ss, (float)Na, (float)Nb);

  pool_k<<<(Na + 1023) / 1024, 256, 0, stream>>>(xa_cur, batch_a, ss_a, ss_a + 128, pool, Na);
  pool_k<<<(Nb + 1023) / 1024, 256, 0, stream>>>(xb_cur, batch_b, ss_b, ss_b + 128, pool, Nb);
  final_k<<<Gn, 64, 0, stream>>>(pool, batch_a, Na, batch_b, Nb,
                                 lin_W, lin_b, (float*)d_out, Cn);
}

// Round 13
// 1054.674 us; speedup vs baseline: 1.4279x; 1.4279x over previous
//
#include <hip/hip_runtime.h>
#include <hip/hip_bf16.h>

#define HF 128

typedef unsigned int uint32;
typedef unsigned short ushort16;
typedef float f32x4 __attribute__((ext_vector_type(4)));
typedef __bf16 bf16x8 __attribute__((ext_vector_type(8)));

// ---- bf16 helpers ----
__device__ __forceinline__ float bflo(uint32 u) { return __uint_as_float(u << 16); }
__device__ __forceinline__ float bfhi(uint32 u) { return __uint_as_float(u & 0xffff0000u); }
__device__ __forceinline__ ushort16 f2bf(float f) {
  uint32 u = __float_as_uint(f);
  return (ushort16)((u + 0x7fffu + ((u >> 16) & 1u)) >> 16);
}
__device__ __forceinline__ uint32 pack2(float lo, float hi) {
  return (uint32)f2bf(lo) | ((uint32)f2bf(hi) << 16);
}

// ---------------------------------------------------------------------------
__global__ void diag_k(float* __restrict__ out, int n, float val) {
  int i = blockIdx.x * 256 + threadIdx.x;
  if (i < n) out[i] = val;
}

// fused setup: conv_a, conv_b, initcs, pool-zero, rp-zero, dummy-row zero
__global__ __launch_bounds__(256) void setup_k(
    const float* __restrict__ xa, const float* __restrict__ xb,
    uint32* __restrict__ XA0, uint32* __restrict__ XA1,
    uint32* __restrict__ XB0, uint32* __restrict__ XB1,
    int n4a, int n4b,
    int* __restrict__ cs, size_t capA, size_t capB, size_t capC, int vA, int vB,
    float* __restrict__ pool, int poolN4,
    int* __restrict__ rpz, int rpN4,
    size_t dummyA, size_t dummyB,
    int CA, int CB, int CI, int PZ, int RZ) {
  int b = blockIdx.x, t = threadIdx.x;
  if (b < CA) {
    int i = b * 256 + t;
    if (i < n4a) {
      float4 v = ((const float4*)xa)[i];
      uint2 p; p.x = pack2(v.x, v.y); p.y = pack2(v.z, v.w);
      ((uint2*)XA0)[i] = p;
    }
    return;
  }
  b -= CA;
  if (b < CB) {
    int i = b * 256 + t;
    if (i < n4b) {
      float4 v = ((const float4*)xb)[i];
      uint2 p; p.x = pack2(v.x, v.y); p.y = pack2(v.z, v.w);
      ((uint2*)XB0)[i] = p;
    }
    return;
  }
  b -= CB;
  if (b < CI) {
    size_t i = ((size_t)b * 256 + t) * 4;
    size_t tot = capA + capB + capC;
    if (i < tot) {
      int v = (i < capA + capB) ? vA : vB;
      int4 w = make_int4(v, v, v, v);
      *(int4*)&cs[i] = w;
    }
    return;
  }
  b -= CI;
  if (b < PZ) {
    int i = b * 256 + t;
    if (i < poolN4) ((float4*)pool)[i] = make_float4(0.f, 0.f, 0.f, 0.f);
    return;
  }
  b -= PZ;
  if (b < RZ) {
    int i = b * 256 + t;
    if (i < rpN4) ((int4*)rpz)[i] = make_int4(0, 0, 0, 0);
    return;
  }
  if (t < 64) XA0[dummyA + t] = 0;
  else if (t < 128) XA1[dummyA + (t - 64)] = 0;
  else if (t < 192) XB0[dummyB + (t - 128)] = 0;
  else XB1[dummyB + (t - 192)] = 0;
}

// ---------------------------------------------------------------------------
// CSR build: fused count (3 types) -> padded hierarchical scan -> fill
__global__ void count3_k(const int* __restrict__ eA, int EA, int* __restrict__ rA,
                         const int* __restrict__ eB, int EB, int* __restrict__ rB,
                         const int* __restrict__ eC, int EC, int* __restrict__ rC,
                         int B0, int B1) {
  int b = blockIdx.x;
  const int* ei; int E; int* rp;
  if (b < B0)            { ei = eA; E = EA; rp = rA; }
  else if (b < B0 + B1)  { ei = eB; E = EB; rp = rB; b -= B0; }
  else                   { ei = eC; E = EC; rp = rC; b -= B0 + B1; }
  int e = b * 256 + threadIdx.x;
  if (e < E) atomicAdd(&rp[ei[E + e]], 1);
}

__device__ __forceinline__ int pad4(int c) { return (c + 3) & ~3; }

__device__ __forceinline__ void scan1_body(const int* __restrict__ rp, int N,
                                           int* __restrict__ bsum, int b, int t) {
  int i = b * 1024 + t * 4;
  int s = 0;
  if (i + 3 < N) {
    int4 v = *(const int4*)&rp[i];
    s = pad4(v.x) + pad4(v.y) + pad4(v.z) + pad4(v.w);
  } else {
    for (int j = 0; j < 4; ++j) if (i + j < N) s += pad4(rp[i + j]);
  }
  __shared__ int sd[256];
  sd[t] = s;
  __syncthreads();
  for (int o = 128; o > 0; o >>= 1) {
    if (t < o) sd[t] += sd[t + o];
    __syncthreads();
  }
  if (t == 0) bsum[b] = sd[0];
}

__global__ __launch_bounds__(256) void scan1x3_k(
    const int* __restrict__ rA, int NA, int* __restrict__ bA,
    const int* __restrict__ rB, int NB, int* __restrict__ bB,
    const int* __restrict__ rC, int NC, int* __restrict__ bC, int nbA, int nbB) {
  int b = blockIdx.x;
  if (b < nbA)            scan1_body(rA, NA, bA, b, threadIdx.x);
  else if (b < nbA + nbB) scan1_body(rB, NB, bB, b - nbA, threadIdx.x);
  else                    scan1_body(rC, NC, bC, b - nbA - nbB, threadIdx.x);
}

__global__ __launch_bounds__(1024) void scan2x3_k(int* __restrict__ bA, int nbA,
                                                  int* __restrict__ bB, int nbB,
                                                  int* __restrict__ bC, int nbC) {
  int* bsum = (blockIdx.x == 0) ? bA : (blockIdx.x == 1) ? bB : bC;
  int nb    = (blockIdx.x == 0) ? nbA : (blockIdx.x == 1) ? nbB : nbC;
  __shared__ int sd[1024];
  int t = threadIdx.x;
  int v = (t < nb) ? bsum[t] : 0;
  sd[t] = v;
  __syncthreads();
  for (int o = 1; o < 1024; o <<= 1) {
    int x = (t >= o) ? sd[t - o] : 0;
    __syncthreads();
    sd[t] += x;
    __syncthreads();
  }
  if (t < nb) bsum[t] = sd[t] - v;
}

__device__ __forceinline__ void scan3_body(int* __restrict__ rp, int* __restrict__ cur,
                                           int* __restrict__ deg,
                                           const int* __restrict__ bsum, int N,
                                           int b, int t) {
  int i = b * 1024 + t * 4;
  int c[4];
  #pragma unroll
  for (int j = 0; j < 4; ++j) c[j] = (i + j < N) ? rp[i + j] : 0;
  int tsum = pad4(c[0]) + pad4(c[1]) + pad4(c[2]) + pad4(c[3]);
  __shared__ int sd[256];
  sd[t] = tsum;
  __syncthreads();
  for (int o = 1; o < 256; o <<= 1) {
    int x = (t >= o) ? sd[t - o] : 0;
    __syncthreads();
    sd[t] += x;
    __syncthreads();
  }
  int off = bsum[b] + sd[t] - tsum;
  int p = off;
  #pragma unroll
  for (int j = 0; j < 4; ++j) {
    if (i + j < N) { rp[i + j] = p; cur[i + j] = p; deg[i + j] = c[j]; }
    p += pad4(c[j]);
  }
  if (i < N && N <= i + 4) rp[N] = off + tsum;
}

__global__ __launch_bounds__(256) void scan3x3_k(
    int* __restrict__ rA, int* __restrict__ cA, int* __restrict__ dA,
    const int* __restrict__ bA, int NA,
    int* __restrict__ rB, int* __restrict__ cB, int* __restrict__ dB,
    const int* __restrict__ bB, int NB,
    int* __restrict__ rC, int* __restrict__ cC, int* __restrict__ dC,
    const int* __restrict__ bC, int NC,
    int nbA, int nbB) {
  int b = blockIdx.x;
  if (b < nbA)            scan3_body(rA, cA, dA, bA, NA, b, threadIdx.x);
  else if (b < nbA + nbB) scan3_body(rB, cB, dB, bB, NB, b - nbA, threadIdx.x);
  else                    scan3_body(rC, cC, dC, bC, NC, b - nbA - nbB, threadIdx.x);
}

#define FILL_P 4
__global__ __launch_bounds__(256) void fill3p_k(
    const int* __restrict__ eA, int EA, int* __restrict__ cuA, int* __restrict__ csA,
    const int* __restrict__ eB, int EB, int* __restrict__ cuB, int* __restrict__ csB,
    const int* __restrict__ eC, int EC, int* __restrict__ cuC, int* __restrict__ csC,
    int NA, int NBn, int B0, int B1, int Btot) {
  int pass = blockIdx.x / Btot;
  int b = blockIdx.x % Btot;
  const int* ei; int E; int* cur; int* cs; int N;
  if (b < B0)           { ei = eA; E = EA; cur = cuA; cs = csA; N = NA; }
  else if (b < B0 + B1) { ei = eB; E = EB; cur = cuB; cs = csB; N = NBn; b -= B0; }
  else                  { ei = eC; E = EC; cur = cuC; cs = csC; N = NA; b -= B0 + B1; }
  int e = b * 256 + threadIdx.x;
  if (e >= E) return;
  int dst = ei[E + e];
  int lo = (int)(((long long)pass * N) / FILL_P);
  int hi = (int)(((long long)(pass + 1) * N) / FILL_P);
  if (dst < lo || dst >= hi) return;
  int pos = atomicAdd(&cur[dst], 1);
  cs[pos] = ei[e];
}

// ---------------------------------------------------------------------------
// per-layer prep: BN finalize + weight pack + u-vectors + zero next stats.
__global__ __launch_bounds__(128) void prep2_k(
    const float* __restrict__ Wrel_l, const float* __restrict__ Wroot_l,
    const float* __restrict__ brel_l,
    const float* __restrict__ gamma, const float* __restrict__ beta,
    const float* __restrict__ statsPrev, float* __restrict__ statsNext,
    float nA, float nB, int first,
    ushort16* __restrict__ BWa, ushort16* __restrict__ BWb,
    float* __restrict__ uvec) {
  __shared__ float red[128];
  int n = blockIdx.x, k = threadIdx.x;
  float scA, shA, scB, shB;
  if (first) {
    scA = 1.f; shA = 0.f; scB = 1.f; shB = 0.f;
  } else {
    float sA = 0.f, qA = 0.f, sB = 0.f, qB = 0.f;
    for (int st = 0; st < 64; ++st) {
      sA += statsPrev[st * 128 + k];
      qA += statsPrev[8192 + st * 128 + k];
      sB += statsPrev[16384 + st * 128 + k];
      qB += statsPrev[24576 + st * 128 + k];
    }
    float mA = sA / nA, vA = qA / nA - mA * mA;
    float rA = rsqrtf(vA + 1e-5f);
    scA = gamma[k] * rA; shA = beta[k] - mA * scA;
    float mB = sB / nB, vB = qB / nB - mB * mB;
    float rB = rsqrtf(vB + 1e-5f);
    scB = gamma[128 + k] * rB; shB = beta[128 + k] - mB * scB;
  }
  if (n < 64) {
    float4 z = make_float4(0.f, 0.f, 0.f, 0.f);
    *(float4*)&statsNext[n * 512 + k * 4] = z;
  }
  float w0  = Wrel_l[n * HF + k];
  float w1  = Wrel_l[16384 + n * HF + k];
  float w2  = Wrel_l[32768 + n * HF + k];
  float wr1 = Wroot_l[16384 + n * HF + k];
  float wrc = Wroot_l[n * HF + k] + Wroot_l[32768 + n * HF + k];

  int ksl = k >> 5;
  int lane = (n & 15) + (((k >> 3) & 3) << 4);
  int j = k & 7;
  int nt = n >> 4;
  auto put = [&](ushort16* B, int ksb, float v) {
    B[((size_t)((ksb + ksl) * 8 + nt) * 64 + lane) * 8 + j] = f2bf(v);
  };
  put(BWa, 0, scA * w0);
  put(BWa, 4, scB * w2);
  put(BWa, 8, scA * wrc);
  put(BWb, 0, scA * w1);
  put(BWb, 4, scB * wr1);

  auto reduce = [&](float v) -> float {
    red[k] = v;
    __syncthreads();
    for (int s = 64; s > 0; s >>= 1) {
      if (k < s) red[k] += red[k + s];
      __syncthreads();
    }
    float r = red[0];
    __syncthreads();
    return r;
  };
  float r0 = reduce(shA * w0);    // uaa
  float r1 = reduce(shB * w2);    // uba
  float r2 = reduce(shA * w1);    // uab
  float r3 = reduce(shA * wrc);   // bias_a extra
  float r4 = reduce(shB * wr1);   // bias_b extra
  if (k == 0) {
    uvec[n]       = r0;
    uvec[128 + n] = r1;
    uvec[256 + n] = r2;
    uvec[384 + n] = brel_l[n] + brel_l[256 + n] + r3;
    uvec[512 + n] = brel_l[128 + n] + r4;
  }
}

// ---------------------------------------------------------------------------
// fused gather + MFMA GEMM + epilogue body. One wave owns 16 output rows.
// Liveness-lean order: gather2 -> park af2 (16 regs) -> gather1 -> af1 ->
// root loads -> MFMA(tile1, tile2, root) -> epilogue (deg loaded there).
// MFMA accumulation order unchanged vs R11 -> identical numerics.
template <bool HAS2>
__device__ __forceinline__ void gg_body(
    int blk,
    const uint32* __restrict__ Xg1, const int* __restrict__ rp1, const int* __restrict__ cs1,
    const int* __restrict__ deg1,
    const uint32* __restrict__ Xg2, const int* __restrict__ rp2, const int* __restrict__ cs2,
    const int* __restrict__ deg2,
    const uint32* Xr,
    const bf16x8* __restrict__ BW,
    const float* __restrict__ u1, const float* __restrict__ u2,
    const float* __restrict__ bias,
    uint32* out,
    float* __restrict__ statS, float* __restrict__ statQ,
    int nRows, uint32* L) {
  constexpr int KS_G = HAS2 ? 8 : 4;
  int tid = threadIdx.x, l = tid & 63, wid = tid >> 6;
  int R0 = blk * 64 + wid * 16;
  int row = l & 15, khi = l >> 4;
  int myRow = R0 + row;
  bool okRow = myRow < nRows;
  int rowIdx = okRow ? myRow : nRows;

  // prologue: row ranges
  int e0a = 0, e1a = 0;
  if (okRow) { e0a = rp1[myRow]; e1a = rp1[myRow + 1]; }
  int e0b = 0, e1b = 0;
  if constexpr (HAS2) { if (okRow) { e0b = rp2[myRow]; e1b = rp2[myRow + 1]; } }

  float lo[16], hi[16];
  auto addv = [&](int base, uint4 v) {
    hi[base + 0] += __uint_as_float(v.x); lo[base + 0] += __uint_as_float(v.x << 16);
    hi[base + 1] += __uint_as_float(v.y); lo[base + 1] += __uint_as_float(v.y << 16);
    hi[base + 2] += __uint_as_float(v.z); lo[base + 2] += __uint_as_float(v.z << 16);
    hi[base + 3] += __uint_as_float(v.w); lo[base + 3] += __uint_as_float(v.w << 16);
  };
  auto run_tile = [&](const uint32* __restrict__ Xg, const int* __restrict__ cs,
                      int e0, int e1) {
    #pragma unroll
    for (int i = 0; i < 16; ++i) { lo[i] = 0.f; hi[i] = 0.f; }
    if (e0 >= e1) return;
    int e = e0;
    int4 q = *(const int4*)&cs[e0];
    for (;;) {
      const uint32* p0 = &Xg[(size_t)q.x * 64 + khi * 4];
      const uint32* p1 = &Xg[(size_t)q.y * 64 + khi * 4];
      const uint32* p2 = &Xg[(size_t)q.z * 64 + khi * 4];
      const uint32* p3 = &Xg[(size_t)q.w * 64 + khi * 4];
      uint4 a0 = *(const uint4*)&p0[0];
      uint4 a1 = *(const uint4*)&p0[16];
      uint4 a2 = *(const uint4*)&p0[32];
      uint4 a3 = *(const uint4*)&p0[48];
      uint4 b0 = *(const uint4*)&p1[0];
      uint4 b1 = *(const uint4*)&p1[16];
      uint4 b2 = *(const uint4*)&p1[32];
      uint4 b3 = *(const uint4*)&p1[48];
      uint4 c0 = *(const uint4*)&p2[0];
      uint4 c1 = *(const uint4*)&p2[16];
      uint4 c2 = *(const uint4*)&p2[32];
      uint4 c3 = *(const uint4*)&p2[48];
      uint4 d0 = *(const uint4*)&p3[0];
      uint4 d1 = *(const uint4*)&p3[16];
      uint4 d2 = *(const uint4*)&p3[32];
      uint4 d3 = *(const uint4*)&p3[48];
      int en = e + 4;
      bool more = en < e1;
      int4 qn = q;
      if (more) qn = *(const int4*)&cs[en];
      addv(0, a0); addv(4, a1); addv(8, a2); addv(12, a3);
      addv(0, b0); addv(4, b1); addv(8, b2); addv(12, b3);
      addv(0, c0); addv(4, c1); addv(8, c2); addv(12, c3);
      addv(0, d0); addv(4, d1); addv(8, d2); addv(12, d3);
      if (!more) break;
      e = en; q = qn;
    }
  };
  auto to_frag = [&](int ks) -> bf16x8 {
    bf16x8 a;
    #pragma unroll
    for (int j = 0; j < 4; ++j) {
      a[2 * j]     = (__bf16)lo[ks * 4 + j];
      a[2 * j + 1] = (__bf16)hi[ks * 4 + j];
    }
    return a;
  };

  // ---- tile 2 gathered FIRST, parked as compact fragments (16 regs) ----
  bf16x8 af2[4];
  if constexpr (HAS2) {
    run_tile(Xg2, cs2, e0b, e1b);
    #pragma unroll
    for (int ks = 0; ks < 4; ++ks) af2[ks] = to_frag(ks);
  }
  // ---- tile 1 ----
  run_tile(Xg1, cs1, e0a, e1a);
  bf16x8 af1[4];
  #pragma unroll
  for (int ks = 0; ks < 4; ++ks) af1[ks] = to_frag(ks);

  // ---- root loads (fly under MFMA1/2) ----
  bf16x8 rt[4];
  #pragma unroll
  for (int ks = 0; ks < 4; ++ks)
    rt[ks] = *(const bf16x8*)&Xr[(size_t)rowIdx * 64 + (ks * 4 + khi) * 4];

  // ---- MFMA phase: tile1 -> tile2 -> root (same order as R11) ----
  f32x4 acc[8] = {};
  const bf16x8* Bl = BW + l;
  #pragma unroll
  for (int ks = 0; ks < 4; ++ks) {
    #pragma unroll
    for (int nt = 0; nt < 8; ++nt) {
      bf16x8 b = Bl[(size_t)(ks * 8 + nt) * 64];
      acc[nt] = __builtin_amdgcn_mfma_f32_16x16x32_bf16(af1[ks], b, acc[nt], 0, 0, 0);
    }
  }
  if constexpr (HAS2) {
    #pragma unroll
    for (int ks = 0; ks < 4; ++ks) {
      #pragma unroll
      for (int nt = 0; nt < 8; ++nt) {
        bf16x8 b = Bl[(size_t)((4 + ks) * 8 + nt) * 64];
        acc[nt] = __builtin_amdgcn_mfma_f32_16x16x32_bf16(af2[ks], b, acc[nt], 0, 0, 0);
      }
    }
  }
  #pragma unroll
  for (int ks = 0; ks < 4; ++ks) {
    #pragma unroll
    for (int nt = 0; nt < 8; ++nt) {
      bf16x8 b = Bl[(size_t)((KS_G + ks) * 8 + nt) * 64];
      acc[nt] = __builtin_amdgcn_mfma_f32_16x16x32_bf16(rt[ks], b, acc[nt], 0, 0, 0);
    }
  }

  // ---- epilogue (deg loaded here) ----
  int rl0 = khi * 4;
  float dg1[4] = {0.f, 0.f, 0.f, 0.f}, dg2[4] = {0.f, 0.f, 0.f, 0.f};
  #pragma unroll
  for (int j = 0; j < 4; ++j) {
    int r = R0 + rl0 + j;
    if (r < nRows) {
      dg1[j] = (float)deg1[r];
      if constexpr (HAS2) dg2[j] = (float)deg2[r];
    }
  }
  ushort16* P = (ushort16*)L;   // [16 rows][stride 136 ushorts]
  int c0 = l & 15;
  float ps[8], pq[8];
  #pragma unroll
  for (int nt = 0; nt < 8; ++nt) {
    int col = nt * 16 + c0;
    float bc = bias[col];
    float u1c = u1[col];
    float u2c = HAS2 ? u2[col] : 0.f;
    float s = 0.f, q = 0.f;
    #pragma unroll
    for (int j = 0; j < 4; ++j) {
      float v = acc[nt][j] + bc + dg1[j] * u1c;
      if constexpr (HAS2) v += dg2[j] * u2c;
      v = fmaxf(v, 0.f);
      if (R0 + rl0 + j < nRows) { s += v; q += v * v; }
      P[(rl0 + j) * 136 + col] = f2bf(v);
    }
    ps[nt] = s; pq[nt] = q;
  }

  #pragma unroll
  for (int rr = 0; rr < 4; ++rr) {
    int rloc = rr * 4 + khi;
    int grow = R0 + rloc;
    if (grow < nRows) {
      uint4 v = *(const uint4*)&P[rloc * 136 + c0 * 8];
      *(uint4*)&out[(size_t)grow * 64 + c0 * 4] = v;
    }
  }

  #pragma unroll
  for (int nt = 0; nt < 8; ++nt) {
    ps[nt] += __shfl_xor(ps[nt], 16); ps[nt] += __shfl_xor(ps[nt], 32);
    pq[nt] += __shfl_xor(pq[nt], 16); pq[nt] += __shfl_xor(pq[nt], 32);
  }
  if (l < 16) {
    float* S = statS + (size_t)(blk & 63) * 128;
    float* Q = statQ + (size_t)(blk & 63) * 128;
    #pragma unroll
    for (int nt = 0; nt < 8; ++nt) {
      unsafeAtomicAdd(&S[nt * 16 + l], ps[nt]);
      unsafeAtomicAdd(&Q[nt * 16 + l], pq[nt]);
    }
  }
}

// merged per-layer kernel: blocks [0,nbA) = type a, [nbA, nbA+nbB) = type b
__global__ __launch_bounds__(256) void gg2_k(
    const uint32* __restrict__ XAc, const uint32* __restrict__ XBc,
    const int* __restrict__ rp_aa, const int* __restrict__ cs_aa, const int* __restrict__ deg_aa,
    const int* __restrict__ rp_ba, const int* __restrict__ cs_ba, const int* __restrict__ deg_ba,
    const int* __restrict__ rp_ab, const int* __restrict__ cs_ab, const int* __restrict__ deg_ab,
    const bf16x8* __restrict__ BWa, const bf16x8* __restrict__ BWb,
    const float* __restrict__ uvec,
    uint32* outA, uint32* outB,
    float* __restrict__ stats,
    int Na, int Nb, int nbA) {
  __shared__ uint32 lds[4][1088];
  uint32* L = &lds[threadIdx.x >> 6][0];
  int b = blockIdx.x;
  if (b < nbA) {
    gg_body<true>(b, XAc, rp_aa, cs_aa, deg_aa, XBc, rp_ba, cs_ba, deg_ba,
                  XAc, BWa, uvec, uvec + 128, uvec + 384, outA,
                  stats, stats + 8192, Na, L);
  } else {
    gg_body<false>(b - nbA, XAc, rp_ab, cs_ab, deg_ab,
                   nullptr, nullptr, nullptr, nullptr,
                   XBc, BWb, uvec + 256, nullptr, uvec + 512, outB,
                   stats + 16384, stats + 24576, Nb, L);
  }
}

// ---------------------------------------------------------------------------
__global__ void bn_fin_k(const float* __restrict__ stats, const float* __restrict__ gamma,
                         const float* __restrict__ beta, float* __restrict__ ss,
                         float nA, float nB) {
  int t = threadIdx.x;
  if (t >= 256) return;
  int type = t >> 7, f = t & 127;
  const float* S = stats + (size_t)type * 16384;
  const float* Q = S + 8192;
  float s = 0.f, q = 0.f;
  for (int st = 0; st < 64; ++st) { s += S[st * 128 + f]; q += Q[st * 128 + f]; }
  float nN = type ? nB : nA;
  float mean = s / nN;
  float var = q / nN - mean * mean;
  float rstd = rsqrtf(var + 1e-5f);
  float sc = gamma[type * HF + f] * rstd;
  float sh = beta[type * HF + f] - mean * sc;
  ss[type * 256 + f] = sc;
  ss[type * 256 + 128 + f] = sh;
}

// ---------------------------------------------------------------------------
__global__ __launch_bounds__(256) void pool_k(const uint32* __restrict__ x,
                                              const int* __restrict__ batch,
                                              const float* __restrict__ scale,
                                              const float* __restrict__ shift,
                                              float* __restrict__ pool, int nN) {
  int f2 = threadIdx.x & 31;
  int sub = threadIdx.x >> 5;
  int start = blockIdx.x * 1024;
  int end = min(start + 1024, nN);
  float4 sc = *(const float4*)&scale[f2 * 4];
  float4 sh = *(const float4*)&shift[f2 * 4];
  float a0 = 0.f, a1 = 0.f, a2 = 0.f, a3 = 0.f, cnt = 0.f;
  int cur = -1;
  for (int n = start + sub; n < end; n += 8) {
    int g = batch[n];
    if (g != cur) {
      if (cur >= 0) {
        float* bp = &pool[(size_t)cur * HF + f2 * 4];
        unsafeAtomicAdd(bp + 0, sc.x * a0 + cnt * sh.x);
        unsafeAtomicAdd(bp + 1, sc.y * a1 + cnt * sh.y);
        unsafeAtomicAdd(bp + 2, sc.z * a2 + cnt * sh.z);
        unsafeAtomicAdd(bp + 3, sc.w * a3 + cnt * sh.w);
      }
      a0 = a1 = a2 = a3 = 0.f; cnt = 0.f; cur = g;
    }
    uint2 v = *(const uint2*)&x[(size_t)n * 64 + f2 * 2];
    a0 += bflo(v.x); a1 += bfhi(v.x); a2 += bflo(v.y); a3 += bfhi(v.y);
    cnt += 1.f;
  }
  if (cur >= 0) {
    float* bp = &pool[(size_t)cur * HF + f2 * 4];
    unsafeAtomicAdd(bp + 0, sc.x * a0 + cnt * sh.x);
    unsafeAtomicAdd(bp + 1, sc.y * a1 + cnt * sh.y);
    unsafeAtomicAdd(bp + 2, sc.z * a2 + cnt * sh.z);
    unsafeAtomicAdd(bp + 3, sc.w * a3 + cnt * sh.w);
  }
}

__device__ inline int lowerb(const int* a, int n, int v) {
  int lo = 0, hi = n;
  while (lo < hi) { int m = (lo + hi) >> 1; if (a[m] < v) lo = m + 1; else hi = m; }
  return lo;
}

__global__ void final_k(const float* __restrict__ pool,
                        const int* __restrict__ ba, int nA,
                        const int* __restrict__ bb, int nB,
                        const float* __restrict__ linW, const float* __restrict__ linb,
                        float* __restrict__ out, int Cn) {
  int g = blockIdx.x;
  int lane = threadIdx.x;
  int c = (lowerb(ba, nA, g + 1) - lowerb(ba, nA, g)) +
          (lowerb(bb, nB, g + 1) - lowerb(bb, nB, g));
  float inv = 1.f / fmaxf((float)c, 1.f);
  float p0 = pool[(size_t)g * HF + lane] * inv;
  float p1 = pool[(size_t)g * HF + 64 + lane] * inv;
  for (int cc = 0; cc < Cn; ++cc) {
    float t = p0 * linW[cc * HF + lane] + p1 * linW[cc * HF + 64 + lane];
    for (int off = 32; off > 0; off >>= 1) t += __shfl_down(t, off);
    if (lane == 0) out[g * Cn + cc] = t + linb[cc];
  }
}

// ---------------------------------------------------------------------------
extern "C" void kernel_launch(void* const* d_in, const int* in_sizes, int n_in,
                              void* d_out, int out_size, void* d_ws, size_t ws_size,
                              hipStream_t stream) {
  const float* x_a   = (const float*)d_in[0];
  const float* x_b   = (const float*)d_in[1];
  const float* Wrel  = (const float*)d_in[2];
  const float* brel  = (const float*)d_in[3];
  const float* Wroot = (const float*)d_in[4];
  const float* bn_g  = (const float*)d_in[5];
  const float* bn_b  = (const float*)d_in[6];
  const float* lin_W = (const float*)d_in[7];
  const float* lin_b = (const float*)d_in[8];
  const int* ei_aa   = (const int*)d_in[9];
  const int* ei_ab   = (const int*)d_in[10];
  const int* ei_ba   = (const int*)d_in[11];
  const int* batch_a = (const int*)d_in[12];
  const int* batch_b = (const int*)d_in[13];

  int Na  = in_sizes[0] / HF;
  int Nb  = in_sizes[1] / HF;
  int Eaa = in_sizes[9] / 2;
  int Eab = in_sizes[10] / 2;
  int Eba = in_sizes[11] / 2;
  int Cn  = in_sizes[7] / HF;
  int Gn  = out_size / Cn;

  size_t NHa = (size_t)Na * HF, NHb = (size_t)Nb * HF;
  size_t capA = ((size_t)Eaa + 3 * (size_t)Na + 15) & ~(size_t)15;
  size_t capB = ((size_t)Eab + 3 * (size_t)Nb + 15) & ~(size_t)15;
  size_t capC = ((size_t)Eba + 3 * (size_t)Na + 15) & ~(size_t)15;

  char* base = (char*)d_ws;
  auto alignup = [](size_t x) { return (x + 255) & ~(size_t)255; };
  size_t off = 0;
  size_t oXA0 = off; off = alignup(off + (NHa + HF) * 2);
  size_t oXA1 = off; off = alignup(off + (NHa + HF) * 2);
  size_t oXB0 = off; off = alignup(off + (NHb + HF) * 2);
  size_t oRP  = off; off = alignup(off + ((size_t)(Na + 1) + (Nb + 1) + (Na + 1)) * 4);
  size_t oCUR = off; off = alignup(off + ((size_t)Na + Nb + Na) * 4);
  size_t oDEG = off; off = alignup(off + ((size_t)Na + Nb + Na) * 4);
  size_t oCS  = off; off = alignup(off + (capA + capB + capC) * 4);
  size_t oBWA = off; off = alignup(off + (size_t)12 * 8 * 64 * 16);
  size_t oBWB = off; off = alignup(off + (size_t)8 * 8 * 64 * 16);
  size_t oUV  = off; off = alignup(off + 5 * 128 * 4);
  size_t oSS  = off; off = alignup(off + 512 * 4);
  size_t oST  = off; off = alignup(off + 65536 * 4);
  size_t oBS  = off; off = alignup(off + 3072 * 4);
  size_t oPOOL= off; off = alignup(off + (size_t)Gn * HF * 4);
  size_t need_min = off;
  size_t oXB1 = off; off = alignup(off + (NHb + HF) * 2);
  size_t need_full = off;

  if (ws_size < need_min) {
    diag_k<<<(out_size + 255) / 256, 256, 0, stream>>>(
        (float*)d_out, out_size, (float)((double)ws_size / 1048576.0));
    return;
  }
  bool merged = ws_size >= need_full;

  uint32* XA0 = (uint32*)(base + oXA0);
  uint32* XA1 = (uint32*)(base + oXA1);
  uint32* XB0 = (uint32*)(base + oXB0);
  uint32* XB1 = merged ? (uint32*)(base + oXB1) : XB0;
  int* rp_aa = (int*)(base + oRP);
  int* rp_ab = rp_aa + (Na + 1);
  int* rp_ba = rp_ab + (Nb + 1);
  int* cur_aa = (int*)(base + oCUR);
  int* cur_ab = cur_aa + Na;
  int* cur_ba = cur_ab + Nb;
  int* deg_aa = (int*)(base + oDEG);
  int* deg_ab = deg_aa + Na;
  int* deg_ba = deg_ab + Nb;
  int* cs_aa = (int*)(base + oCS);
  int* cs_ab = cs_aa + capA;
  int* cs_ba = cs_ab + capB;
  ushort16* BWa = (ushort16*)(base + oBWA);
  ushort16* BWb = (ushort16*)(base + oBWB);
  float* uvec  = (float*)(base + oUV);
  float* ss    = (float*)(base + oSS);
  float* stats = (float*)(base + oST);
  int* bsum    = (int*)(base + oBS);
  float* pool  = (float*)(base + oPOOL);

  float* ss_a = ss;
  float* ss_b = ss + 256;

  int n4a = (int)(NHa / 4), n4b = (int)(NHb / 4);
  int CA = (n4a + 255) / 256, CB = (n4b + 255) / 256;
  size_t capTot = capA + capB + capC;
  int CI = (int)((capTot / 4 + 255) / 256);
  int poolN4 = Gn * HF / 4;
  int PZ = (poolN4 + 255) / 256;
  int rpCnt = (Na + 1) + (Nb + 1) + (Na + 1);
  int rpN4 = (rpCnt + 3) / 4;
  int RZ = (rpN4 + 255) / 256;
  setup_k<<<CA + CB + CI + PZ + RZ + 1, 256, 0, stream>>>(
      x_a, x_b, XA0, XA1, XB0, XB1, n4a, n4b,
      cs_aa, capA, capB, capC, Na, Nb,
      pool, poolN4, rp_aa, rpN4,
      NHa / 2, NHb / 2, CA, CB, CI, PZ, RZ);

  int B0 = (Eaa + 255) / 256, B1 = (Eab + 255) / 256, B2 = (Eba + 255) / 256;
  count3_k<<<B0 + B1 + B2, 256, 0, stream>>>(ei_aa, Eaa, rp_aa, ei_ab, Eab, rp_ab,
                                             ei_ba, Eba, rp_ba, B0, B1);

  int nb_a = (Na + 1023) / 1024;
  int nb_b = (Nb + 1023) / 1024;
  scan1x3_k<<<nb_a + nb_b + nb_a, 256, 0, stream>>>(
      rp_aa, Na, bsum, rp_ab, Nb, bsum + 1024, rp_ba, Na, bsum + 2048, nb_a, nb_b);
  scan2x3_k<<<3, 1024, 0, stream>>>(bsum, nb_a, bsum + 1024, nb_b, bsum + 2048, nb_a);
  scan3x3_k<<<nb_a + nb_b + nb_a, 256, 0, stream>>>(
      rp_aa, cur_aa, deg_aa, bsum, Na,
      rp_ab, cur_ab, deg_ab, bsum + 1024, Nb,
      rp_ba, cur_ba, deg_ba, bsum + 2048, Na, nb_a, nb_b);

  int Btot = B0 + B1 + B2;
  fill3p_k<<<FILL_P * Btot, 256, 0, stream>>>(ei_aa, Eaa, cur_aa, cs_aa,
                                              ei_ab, Eab, cur_ab, cs_ab,
                                              ei_ba, Eba, cur_ba, cs_ba,
                                              Na, Nb, B0, B1, Btot);

  int nbA = (Na + 63) / 64;
  int nbB = (Nb + 63) / 64;
  uint32* xa_cur = XA0;
  uint32* xa_nxt = XA1;
  uint32* xb_cur = XB0;
  uint32* xb_nxt = XB1;
  for (int l = 0; l < 3; ++l) {
    const float* Wrel_l  = Wrel  + (size_t)l * 3 * 16384;
    const float* Wroot_l = Wroot + (size_t)l * 3 * 16384;
    const float* brel_l  = brel  + (size_t)l * 3 * HF;
    float* statsCur  = stats + (size_t)(l & 1) * 32768;
    float* statsPrev = stats + (size_t)((l + 1) & 1) * 32768;

    prep2_k<<<128, 128, 0, stream>>>(Wrel_l, Wroot_l, brel_l, bn_g, bn_b,
                                     statsPrev, statsCur, (float)Na, (float)Nb,
                                     (l == 0) ? 1 : 0, BWa, BWb, uvec);

    if (merged) {
      gg2_k<<<nbA + nbB, 256, 0, stream>>>(
          xa_cur, xb_cur, rp_aa, cs_aa, deg_aa, rp_ba, cs_ba, deg_ba,
          rp_ab, cs_ab, deg_ab,
          (const bf16x8*)BWa, (const bf16x8*)BWb, uvec,
          xa_nxt, xb_nxt, statsCur, Na, Nb, nbA);
      uint32* t2 = xb_cur; xb_cur = xb_nxt; xb_nxt = t2;
    } else {
      gg2_k<<<nbA, 256, 0, stream>>>(
          xa_cur, xb_cur, rp_aa, cs_aa, deg_aa, rp_ba, cs_ba, deg_ba,
          rp_ab, cs_ab, deg_ab,
          (const bf16x8*)BWa, (const bf16x8*)BWb, uvec,
          xa_nxt, nullptr, statsCur, Na, Nb, nbA);
      gg2_k<<<nbB, 256, 0, stream>>>(
          xa_cur, xb_cur, rp_aa, cs_aa, deg_aa, rp_ba, cs_ba, deg_ba,
          rp_ab, cs_ab, deg_ab,
          (const bf16x8*)BWa, (const bf16x8*)BWb, uvec,
          nullptr, xb_cur, statsCur, Na, Nb, 0);
    }
    uint32* t = xa_cur; xa_cur = xa_nxt; xa_nxt = t;
  }

  bn_fin_k<<<1, 256, 0, stream>>>(stats, bn_g, bn_b, ss, (float)Na, (float)Nb);

  pool_k<<<(Na + 1023) / 1024, 256, 0, stream>>>(xa_cur, batch_a, ss_a, ss_a + 128, pool, Na);
  pool_k<<<(Nb + 1023) / 1024, 256, 0, stream>>>(xb_cur, batch_b, ss_b, ss_b + 128, pool, Nb);
  final_k<<<Gn, 64, 0, stream>>>(pool, batch_a, Na, batch_b, Nb,
                                 lin_W, lin_b, (float*)d_out, Cn);
}

// Round 14
// 926.861 us; speedup vs baseline: 1.6248x; 1.1379x over previous
//
#include <hip/hip_runtime.h>
#include <hip/hip_bf16.h>

#define HF 128

typedef unsigned int uint32;
typedef unsigned short ushort16;
typedef float f32x4 __attribute__((ext_vector_type(4)));
typedef __bf16 bf16x8 __attribute__((ext_vector_type(8)));

// ---- bf16 helpers ----
__device__ __forceinline__ float bflo(uint32 u) { return __uint_as_float(u << 16); }
__device__ __forceinline__ float bfhi(uint32 u) { return __uint_as_float(u & 0xffff0000u); }
__device__ __forceinline__ ushort16 f2bf(float f) {
  uint32 u = __float_as_uint(f);
  return (ushort16)((u + 0x7fffu + ((u >> 16) & 1u)) >> 16);
}
__device__ __forceinline__ uint32 pack2(float lo, float hi) {
  return (uint32)f2bf(lo) | ((uint32)f2bf(hi) << 16);
}

// ---------------------------------------------------------------------------
__global__ void diag_k(float* __restrict__ out, int n, float val) {
  int i = blockIdx.x * 256 + threadIdx.x;
  if (i < n) out[i] = val;
}

// fused setup: conv_a, conv_b, initcs, pool-zero, rp-zero, dummy-row zero
__global__ __launch_bounds__(256) void setup_k(
    const float* __restrict__ xa, const float* __restrict__ xb,
    uint32* __restrict__ XA0, uint32* __restrict__ XA1,
    uint32* __restrict__ XB0, uint32* __restrict__ XB1,
    int n4a, int n4b,
    int* __restrict__ cs, size_t capA, size_t capB, size_t capC, int vA, int vB,
    float* __restrict__ pool, int poolN4,
    int* __restrict__ rpz, int rpN4,
    size_t dummyA, size_t dummyB,
    int CA, int CB, int CI, int PZ, int RZ) {
  int b = blockIdx.x, t = threadIdx.x;
  if (b < CA) {
    int i = b * 256 + t;
    if (i < n4a) {
      float4 v = ((const float4*)xa)[i];
      uint2 p; p.x = pack2(v.x, v.y); p.y = pack2(v.z, v.w);
      ((uint2*)XA0)[i] = p;
    }
    return;
  }
  b -= CA;
  if (b < CB) {
    int i = b * 256 + t;
    if (i < n4b) {
      float4 v = ((const float4*)xb)[i];
      uint2 p; p.x = pack2(v.x, v.y); p.y = pack2(v.z, v.w);
      ((uint2*)XB0)[i] = p;
    }
    return;
  }
  b -= CB;
  if (b < CI) {
    size_t i = ((size_t)b * 256 + t) * 4;
    size_t tot = capA + capB + capC;
    if (i < tot) {
      int v = (i < capA + capB) ? vA : vB;
      int4 w = make_int4(v, v, v, v);
      *(int4*)&cs[i] = w;
    }
    return;
  }
  b -= CI;
  if (b < PZ) {
    int i = b * 256 + t;
    if (i < poolN4) ((float4*)pool)[i] = make_float4(0.f, 0.f, 0.f, 0.f);
    return;
  }
  b -= PZ;
  if (b < RZ) {
    int i = b * 256 + t;
    if (i < rpN4) ((int4*)rpz)[i] = make_int4(0, 0, 0, 0);
    return;
  }
  if (t < 64) XA0[dummyA + t] = 0;
  else if (t < 128) XA1[dummyA + (t - 64)] = 0;
  else if (t < 192) XB0[dummyB + (t - 128)] = 0;
  else XB1[dummyB + (t - 192)] = 0;
}

// ---------------------------------------------------------------------------
// CSR build: fused count (3 types) -> padded hierarchical scan -> fill
__global__ void count3_k(const int* __restrict__ eA, int EA, int* __restrict__ rA,
                         const int* __restrict__ eB, int EB, int* __restrict__ rB,
                         const int* __restrict__ eC, int EC, int* __restrict__ rC,
                         int B0, int B1) {
  int b = blockIdx.x;
  const int* ei; int E; int* rp;
  if (b < B0)            { ei = eA; E = EA; rp = rA; }
  else if (b < B0 + B1)  { ei = eB; E = EB; rp = rB; b -= B0; }
  else                   { ei = eC; E = EC; rp = rC; b -= B0 + B1; }
  int e = b * 256 + threadIdx.x;
  if (e < E) atomicAdd(&rp[ei[E + e]], 1);
}

__device__ __forceinline__ int pad4(int c) { return (c + 3) & ~3; }

__device__ __forceinline__ void scan1_body(const int* __restrict__ rp, int N,
                                           int* __restrict__ bsum, int b, int t) {
  int i = b * 1024 + t * 4;
  int s = 0;
  if (i + 3 < N) {
    int4 v = *(const int4*)&rp[i];
    s = pad4(v.x) + pad4(v.y) + pad4(v.z) + pad4(v.w);
  } else {
    for (int j = 0; j < 4; ++j) if (i + j < N) s += pad4(rp[i + j]);
  }
  __shared__ int sd[256];
  sd[t] = s;
  __syncthreads();
  for (int o = 128; o > 0; o >>= 1) {
    if (t < o) sd[t] += sd[t + o];
    __syncthreads();
  }
  if (t == 0) bsum[b] = sd[0];
}

__global__ __launch_bounds__(256) void scan1x3_k(
    const int* __restrict__ rA, int NA, int* __restrict__ bA,
    const int* __restrict__ rB, int NB, int* __restrict__ bB,
    const int* __restrict__ rC, int NC, int* __restrict__ bC, int nbA, int nbB) {
  int b = blockIdx.x;
  if (b < nbA)            scan1_body(rA, NA, bA, b, threadIdx.x);
  else if (b < nbA + nbB) scan1_body(rB, NB, bB, b - nbA, threadIdx.x);
  else                    scan1_body(rC, NC, bC, b - nbA - nbB, threadIdx.x);
}

__global__ __launch_bounds__(1024) void scan2x3_k(int* __restrict__ bA, int nbA,
                                                  int* __restrict__ bB, int nbB,
                                                  int* __restrict__ bC, int nbC) {
  int* bsum = (blockIdx.x == 0) ? bA : (blockIdx.x == 1) ? bB : bC;
  int nb    = (blockIdx.x == 0) ? nbA : (blockIdx.x == 1) ? nbB : nbC;
  __shared__ int sd[1024];
  int t = threadIdx.x;
  int v = (t < nb) ? bsum[t] : 0;
  sd[t] = v;
  __syncthreads();
  for (int o = 1; o < 1024; o <<= 1) {
    int x = (t >= o) ? sd[t - o] : 0;
    __syncthreads();
    sd[t] += x;
    __syncthreads();
  }
  if (t < nb) bsum[t] = sd[t] - v;
}

__device__ __forceinline__ void scan3_body(int* __restrict__ rp, int* __restrict__ cur,
                                           int* __restrict__ deg,
                                           const int* __restrict__ bsum, int N,
                                           int b, int t) {
  int i = b * 1024 + t * 4;
  int c[4];
  #pragma unroll
  for (int j = 0; j < 4; ++j) c[j] = (i + j < N) ? rp[i + j] : 0;
  int tsum = pad4(c[0]) + pad4(c[1]) + pad4(c[2]) + pad4(c[3]);
  __shared__ int sd[256];
  sd[t] = tsum;
  __syncthreads();
  for (int o = 1; o < 256; o <<= 1) {
    int x = (t >= o) ? sd[t - o] : 0;
    __syncthreads();
    sd[t] += x;
    __syncthreads();
  }
  int off = bsum[b] + sd[t] - tsum;
  int p = off;
  #pragma unroll
  for (int j = 0; j < 4; ++j) {
    if (i + j < N) { rp[i + j] = p; cur[i + j] = p; deg[i + j] = c[j]; }
    p += pad4(c[j]);
  }
  if (i < N && N <= i + 4) rp[N] = off + tsum;
}

__global__ __launch_bounds__(256) void scan3x3_k(
    int* __restrict__ rA, int* __restrict__ cA, int* __restrict__ dA,
    const int* __restrict__ bA, int NA,
    int* __restrict__ rB, int* __restrict__ cB, int* __restrict__ dB,
    const int* __restrict__ bB, int NB,
    int* __restrict__ rC, int* __restrict__ cC, int* __restrict__ dC,
    const int* __restrict__ bC, int NC,
    int nbA, int nbB) {
  int b = blockIdx.x;
  if (b < nbA)            scan3_body(rA, cA, dA, bA, NA, b, threadIdx.x);
  else if (b < nbA + nbB) scan3_body(rB, cB, dB, bB, NB, b - nbA, threadIdx.x);
  else                    scan3_body(rC, cC, dC, bC, NC, b - nbA - nbB, threadIdx.x);
}

#define FILL_P 4
__global__ __launch_bounds__(256) void fill3p_k(
    const int* __restrict__ eA, int EA, int* __restrict__ cuA, int* __restrict__ csA,
    const int* __restrict__ eB, int EB, int* __restrict__ cuB, int* __restrict__ csB,
    const int* __restrict__ eC, int EC, int* __restrict__ cuC, int* __restrict__ csC,
    int NA, int NBn, int B0, int B1, int Btot) {
  int pass = blockIdx.x / Btot;
  int b = blockIdx.x % Btot;
  const int* ei; int E; int* cur; int* cs; int N;
  if (b < B0)           { ei = eA; E = EA; cur = cuA; cs = csA; N = NA; }
  else if (b < B0 + B1) { ei = eB; E = EB; cur = cuB; cs = csB; N = NBn; b -= B0; }
  else                  { ei = eC; E = EC; cur = cuC; cs = csC; N = NA; b -= B0 + B1; }
  int e = b * 256 + threadIdx.x;
  if (e >= E) return;
  int dst = ei[E + e];
  int lo = (int)(((long long)pass * N) / FILL_P);
  int hi = (int)(((long long)(pass + 1) * N) / FILL_P);
  if (dst < lo || dst >= hi) return;
  int pos = atomicAdd(&cur[dst], 1);
  cs[pos] = ei[e];
}

// ---------------------------------------------------------------------------
// per-layer prep: BN finalize + weight pack + u-vectors + zero next stats.
__global__ __launch_bounds__(128) void prep2_k(
    const float* __restrict__ Wrel_l, const float* __restrict__ Wroot_l,
    const float* __restrict__ brel_l,
    const float* __restrict__ gamma, const float* __restrict__ beta,
    const float* __restrict__ statsPrev, float* __restrict__ statsNext,
    float nA, float nB, int first,
    ushort16* __restrict__ BWa, ushort16* __restrict__ BWb,
    float* __restrict__ uvec) {
  __shared__ float red[128];
  int n = blockIdx.x, k = threadIdx.x;
  float scA, shA, scB, shB;
  if (first) {
    scA = 1.f; shA = 0.f; scB = 1.f; shB = 0.f;
  } else {
    float sA = 0.f, qA = 0.f, sB = 0.f, qB = 0.f;
    for (int st = 0; st < 64; ++st) {
      sA += statsPrev[st * 128 + k];
      qA += statsPrev[8192 + st * 128 + k];
      sB += statsPrev[16384 + st * 128 + k];
      qB += statsPrev[24576 + st * 128 + k];
    }
    float mA = sA / nA, vA = qA / nA - mA * mA;
    float rA = rsqrtf(vA + 1e-5f);
    scA = gamma[k] * rA; shA = beta[k] - mA * scA;
    float mB = sB / nB, vB = qB / nB - mB * mB;
    float rB = rsqrtf(vB + 1e-5f);
    scB = gamma[128 + k] * rB; shB = beta[128 + k] - mB * scB;
  }
  if (n < 64) {
    float4 z = make_float4(0.f, 0.f, 0.f, 0.f);
    *(float4*)&statsNext[n * 512 + k * 4] = z;
  }
  float w0  = Wrel_l[n * HF + k];
  float w1  = Wrel_l[16384 + n * HF + k];
  float w2  = Wrel_l[32768 + n * HF + k];
  float wr1 = Wroot_l[16384 + n * HF + k];
  float wrc = Wroot_l[n * HF + k] + Wroot_l[32768 + n * HF + k];

  int ksl = k >> 5;
  int lane = (n & 15) + (((k >> 3) & 3) << 4);
  int j = k & 7;
  int nt = n >> 4;
  auto put = [&](ushort16* B, int ksb, float v) {
    B[((size_t)((ksb + ksl) * 8 + nt) * 64 + lane) * 8 + j] = f2bf(v);
  };
  put(BWa, 0, scA * w0);
  put(BWa, 4, scB * w2);
  put(BWa, 8, scA * wrc);
  put(BWb, 0, scA * w1);
  put(BWb, 4, scB * wr1);

  auto reduce = [&](float v) -> float {
    red[k] = v;
    __syncthreads();
    for (int s = 64; s > 0; s >>= 1) {
      if (k < s) red[k] += red[k + s];
      __syncthreads();
    }
    float r = red[0];
    __syncthreads();
    return r;
  };
  float r0 = reduce(shA * w0);    // uaa
  float r1 = reduce(shB * w2);    // uba
  float r2 = reduce(shA * w1);    // uab
  float r3 = reduce(shA * wrc);   // bias_a extra
  float r4 = reduce(shB * wr1);   // bias_b extra
  if (k == 0) {
    uvec[n]       = r0;
    uvec[128 + n] = r1;
    uvec[256 + n] = r2;
    uvec[384 + n] = brel_l[n] + brel_l[256 + n] + r3;
    uvec[512 + n] = brel_l[128 + n] + r4;
  }
}

// ---------------------------------------------------------------------------
// fused gather + MFMA GEMM + epilogue body. One wave owns 16 output rows.
// Prologue issues ALL independent long-latency loads (rp1,rp2,root,first cs
// quads,deg) before any consumption -> collapses the rp->cs->X serial chain.
template <bool HAS2>
__device__ __forceinline__ void gg_body(
    int blk,
    const uint32* __restrict__ Xg1, const int* __restrict__ rp1, const int* __restrict__ cs1,
    const int* __restrict__ deg1,
    const uint32* __restrict__ Xg2, const int* __restrict__ rp2, const int* __restrict__ cs2,
    const int* __restrict__ deg2,
    const uint32* Xr,
    const bf16x8* __restrict__ BW,
    const float* __restrict__ u1, const float* __restrict__ u2,
    const float* __restrict__ bias,
    uint32* out,
    float* __restrict__ statS, float* __restrict__ statQ,
    int nRows, uint32* L) {
  constexpr int KS_G = HAS2 ? 8 : 4;
  int tid = threadIdx.x, l = tid & 63, wid = tid >> 6;
  int R0 = blk * 64 + wid * 16;
  int row = l & 15, khi = l >> 4;
  int myRow = R0 + row;
  bool okRow = myRow < nRows;
  int rowIdx = okRow ? myRow : nRows;

  // ---- prologue: all independent long-latency loads ----
  int e0a = 0, e1a = 0;
  if (okRow) { e0a = rp1[myRow]; e1a = rp1[myRow + 1]; }
  int e0b = 0, e1b = 0;
  if constexpr (HAS2) { if (okRow) { e0b = rp2[myRow]; e1b = rp2[myRow + 1]; } }
  bf16x8 rt[4];
  #pragma unroll
  for (int ks = 0; ks < 4; ++ks)
    rt[ks] = *(const bf16x8*)&Xr[(size_t)rowIdx * 64 + (ks * 4 + khi) * 4];
  int4 q1 = make_int4(0, 0, 0, 0), q2 = make_int4(0, 0, 0, 0);
  if (e0a < e1a) q1 = *(const int4*)&cs1[e0a];
  if constexpr (HAS2) { if (e0b < e1b) q2 = *(const int4*)&cs2[e0b]; }
  int rl0 = khi * 4;
  float dg1[4] = {0.f, 0.f, 0.f, 0.f}, dg2[4] = {0.f, 0.f, 0.f, 0.f};
  #pragma unroll
  for (int j = 0; j < 4; ++j) {
    int r = R0 + rl0 + j;
    if (r < nRows) {
      dg1[j] = (float)deg1[r];
      if constexpr (HAS2) dg2[j] = (float)deg2[r];
    }
  }

  float lo[16], hi[16];
  auto addv = [&](int base, uint4 v) {
    hi[base + 0] += __uint_as_float(v.x); lo[base + 0] += __uint_as_float(v.x << 16);
    hi[base + 1] += __uint_as_float(v.y); lo[base + 1] += __uint_as_float(v.y << 16);
    hi[base + 2] += __uint_as_float(v.z); lo[base + 2] += __uint_as_float(v.z << 16);
    hi[base + 3] += __uint_as_float(v.w); lo[base + 3] += __uint_as_float(v.w << 16);
  };
  auto run_tile = [&](const uint32* __restrict__ Xg, const int* __restrict__ cs,
                      int e0, int e1, int4 qinit) {
    #pragma unroll
    for (int i = 0; i < 16; ++i) { lo[i] = 0.f; hi[i] = 0.f; }
    if (e0 >= e1) return;
    int e = e0;
    int4 q = qinit;
    for (;;) {
      const uint32* p0 = &Xg[(size_t)q.x * 64 + khi * 4];
      const uint32* p1 = &Xg[(size_t)q.y * 64 + khi * 4];
      const uint32* p2 = &Xg[(size_t)q.z * 64 + khi * 4];
      const uint32* p3 = &Xg[(size_t)q.w * 64 + khi * 4];
      uint4 a0 = *(const uint4*)&p0[0];
      uint4 a1 = *(const uint4*)&p0[16];
      uint4 a2 = *(const uint4*)&p0[32];
      uint4 a3 = *(const uint4*)&p0[48];
      uint4 b0 = *(const uint4*)&p1[0];
      uint4 b1 = *(const uint4*)&p1[16];
      uint4 b2 = *(const uint4*)&p1[32];
      uint4 b3 = *(const uint4*)&p1[48];
      uint4 c0 = *(const uint4*)&p2[0];
      uint4 c1 = *(const uint4*)&p2[16];
      uint4 c2 = *(const uint4*)&p2[32];
      uint4 c3 = *(const uint4*)&p2[48];
      uint4 d0 = *(const uint4*)&p3[0];
      uint4 d1 = *(const uint4*)&p3[16];
      uint4 d2 = *(const uint4*)&p3[32];
      uint4 d3 = *(const uint4*)&p3[48];
      int en = e + 4;
      bool more = en < e1;
      int4 qn = q;
      if (more) qn = *(const int4*)&cs[en];
      addv(0, a0); addv(4, a1); addv(8, a2); addv(12, a3);
      addv(0, b0); addv(4, b1); addv(8, b2); addv(12, b3);
      addv(0, c0); addv(4, c1); addv(8, c2); addv(12, c3);
      addv(0, d0); addv(4, d1); addv(8, d2); addv(12, d3);
      if (!more) break;
      e = en; q = qn;
    }
  };
  auto to_frag = [&](int ks) -> bf16x8 {
    bf16x8 a;
    #pragma unroll
    for (int j = 0; j < 4; ++j) {
      a[2 * j]     = (__bf16)lo[ks * 4 + j];
      a[2 * j + 1] = (__bf16)hi[ks * 4 + j];
    }
    return a;
  };

  // gather both tiles first (tile2's index chain resolved in prologue)
  run_tile(Xg1, cs1, e0a, e1a, q1);
  bf16x8 af1[4];
  #pragma unroll
  for (int ks = 0; ks < 4; ++ks) af1[ks] = to_frag(ks);

  bf16x8 af2[4];
  if constexpr (HAS2) {
    run_tile(Xg2, cs2, e0b, e1b, q2);
    #pragma unroll
    for (int ks = 0; ks < 4; ++ks) af2[ks] = to_frag(ks);
  }

  // ---- MFMA phase (all fragments ready) ----
  f32x4 acc[8] = {};
  const bf16x8* Bl = BW + l;
  #pragma unroll
  for (int ks = 0; ks < 4; ++ks) {
    #pragma unroll
    for (int nt = 0; nt < 8; ++nt) {
      bf16x8 b = Bl[(size_t)(ks * 8 + nt) * 64];
      acc[nt] = __builtin_amdgcn_mfma_f32_16x16x32_bf16(af1[ks], b, acc[nt], 0, 0, 0);
    }
  }
  if constexpr (HAS2) {
    #pragma unroll
    for (int ks = 0; ks < 4; ++ks) {
      #pragma unroll
      for (int nt = 0; nt < 8; ++nt) {
        bf16x8 b = Bl[(size_t)((4 + ks) * 8 + nt) * 64];
        acc[nt] = __builtin_amdgcn_mfma_f32_16x16x32_bf16(af2[ks], b, acc[nt], 0, 0, 0);
      }
    }
  }
  #pragma unroll
  for (int ks = 0; ks < 4; ++ks) {
    #pragma unroll
    for (int nt = 0; nt < 8; ++nt) {
      bf16x8 b = Bl[(size_t)((KS_G + ks) * 8 + nt) * 64];
      acc[nt] = __builtin_amdgcn_mfma_f32_16x16x32_bf16(rt[ks], b, acc[nt], 0, 0, 0);
    }
  }

  // ---- epilogue ----
  ushort16* P = (ushort16*)L;   // [16 rows][stride 136 ushorts]
  int c0 = l & 15;
  float ps[8], pq[8];
  #pragma unroll
  for (int nt = 0; nt < 8; ++nt) {
    int col = nt * 16 + c0;
    float bc = bias[col];
    float u1c = u1[col];
    float u2c = HAS2 ? u2[col] : 0.f;
    float s = 0.f, q = 0.f;
    #pragma unroll
    for (int j = 0; j < 4; ++j) {
      float v = acc[nt][j] + bc + dg1[j] * u1c;
      if constexpr (HAS2) v += dg2[j] * u2c;
      v = fmaxf(v, 0.f);
      if (R0 + rl0 + j < nRows) { s += v; q += v * v; }
      P[(rl0 + j) * 136 + col] = f2bf(v);
    }
    ps[nt] = s; pq[nt] = q;
  }

  #pragma unroll
  for (int rr = 0; rr < 4; ++rr) {
    int rloc = rr * 4 + khi;
    int grow = R0 + rloc;
    if (grow < nRows) {
      uint4 v = *(const uint4*)&P[rloc * 136 + c0 * 8];
      *(uint4*)&out[(size_t)grow * 64 + c0 * 4] = v;
    }
  }

  #pragma unroll
  for (int nt = 0; nt < 8; ++nt) {
    ps[nt] += __shfl_xor(ps[nt], 16); ps[nt] += __shfl_xor(ps[nt], 32);
    pq[nt] += __shfl_xor(pq[nt], 16); pq[nt] += __shfl_xor(pq[nt], 32);
  }
  if (l < 16) {
    float* S = statS + (size_t)(blk & 63) * 128;
    float* Q = statQ + (size_t)(blk & 63) * 128;
    #pragma unroll
    for (int nt = 0; nt < 8; ++nt) {
      unsafeAtomicAdd(&S[nt * 16 + l], ps[nt]);
      unsafeAtomicAdd(&Q[nt * 16 + l], pq[nt]);
    }
  }
}

// merged per-layer kernel: blocks [0,nbA) = type a, [nbA, nbA+nbB) = type b
__global__ __launch_bounds__(256) void gg2_k(
    const uint32* __restrict__ XAc, const uint32* __restrict__ XBc,
    const int* __restrict__ rp_aa, const int* __restrict__ cs_aa, const int* __restrict__ deg_aa,
    const int* __restrict__ rp_ba, const int* __restrict__ cs_ba, const int* __restrict__ deg_ba,
    const int* __restrict__ rp_ab, const int* __restrict__ cs_ab, const int* __restrict__ deg_ab,
    const bf16x8* __restrict__ BWa, const bf16x8* __restrict__ BWb,
    const float* __restrict__ uvec,
    uint32* outA, uint32* outB,
    float* __restrict__ stats,
    int Na, int Nb, int nbA) {
  __shared__ uint32 lds[4][1088];
  uint32* L = &lds[threadIdx.x >> 6][0];
  int b = blockIdx.x;
  if (b < nbA) {
    gg_body<true>(b, XAc, rp_aa, cs_aa, deg_aa, XBc, rp_ba, cs_ba, deg_ba,
                  XAc, BWa, uvec, uvec + 128, uvec + 384, outA,
                  stats, stats + 8192, Na, L);
  } else {
    gg_body<false>(b - nbA, XAc, rp_ab, cs_ab, deg_ab,
                   nullptr, nullptr, nullptr, nullptr,
                   XBc, BWb, uvec + 256, nullptr, uvec + 512, outB,
                   stats + 16384, stats + 24576, Nb, L);
  }
}

// ---------------------------------------------------------------------------
__global__ void bn_fin_k(const float* __restrict__ stats, const float* __restrict__ gamma,
                         const float* __restrict__ beta, float* __restrict__ ss,
                         float nA, float nB) {
  int t = threadIdx.x;
  if (t >= 256) return;
  int type = t >> 7, f = t & 127;
  const float* S = stats + (size_t)type * 16384;
  const float* Q = S + 8192;
  float s = 0.f, q = 0.f;
  for (int st = 0; st < 64; ++st) { s += S[st * 128 + f]; q += Q[st * 128 + f]; }
  float nN = type ? nB : nA;
  float mean = s / nN;
  float var = q / nN - mean * mean;
  float rstd = rsqrtf(var + 1e-5f);
  float sc = gamma[type * HF + f] * rstd;
  float sh = beta[type * HF + f] - mean * sc;
  ss[type * 256 + f] = sc;
  ss[type * 256 + 128 + f] = sh;
}

// ---------------------------------------------------------------------------
__global__ __launch_bounds__(256) void pool_k(const uint32* __restrict__ x,
                                              const int* __restrict__ batch,
                                              const float* __restrict__ scale,
                                              const float* __restrict__ shift,
                                              float* __restrict__ pool, int nN) {
  int f2 = threadIdx.x & 31;
  int sub = threadIdx.x >> 5;
  int start = blockIdx.x * 1024;
  int end = min(start + 1024, nN);
  float4 sc = *(const float4*)&scale[f2 * 4];
  float4 sh = *(const float4*)&shift[f2 * 4];
  float a0 = 0.f, a1 = 0.f, a2 = 0.f, a3 = 0.f, cnt = 0.f;
  int cur = -1;
  for (int n = start + sub; n < end; n += 8) {
    int g = batch[n];
    if (g != cur) {
      if (cur >= 0) {
        float* bp = &pool[(size_t)cur * HF + f2 * 4];
        unsafeAtomicAdd(bp + 0, sc.x * a0 + cnt * sh.x);
        unsafeAtomicAdd(bp + 1, sc.y * a1 + cnt * sh.y);
        unsafeAtomicAdd(bp + 2, sc.z * a2 + cnt * sh.z);
        unsafeAtomicAdd(bp + 3, sc.w * a3 + cnt * sh.w);
      }
      a0 = a1 = a2 = a3 = 0.f; cnt = 0.f; cur = g;
    }
    uint2 v = *(const uint2*)&x[(size_t)n * 64 + f2 * 2];
    a0 += bflo(v.x); a1 += bfhi(v.x); a2 += bflo(v.y); a3 += bfhi(v.y);
    cnt += 1.f;
  }
  if (cur >= 0) {
    float* bp = &pool[(size_t)cur * HF + f2 * 4];
    unsafeAtomicAdd(bp + 0, sc.x * a0 + cnt * sh.x);
    unsafeAtomicAdd(bp + 1, sc.y * a1 + cnt * sh.y);
    unsafeAtomicAdd(bp + 2, sc.z * a2 + cnt * sh.z);
    unsafeAtomicAdd(bp + 3, sc.w * a3 + cnt * sh.w);
  }
}

__device__ inline int lowerb(const int* a, int n, int v) {
  int lo = 0, hi = n;
  while (lo < hi) { int m = (lo + hi) >> 1; if (a[m] < v) lo = m + 1; else hi = m; }
  return lo;
}

__global__ void final_k(const float* __restrict__ pool,
                        const int* __restrict__ ba, int nA,
                        const int* __restrict__ bb, int nB,
                        const float* __restrict__ linW, const float* __restrict__ linb,
                        float* __restrict__ out, int Cn) {
  int g = blockIdx.x;
  int lane = threadIdx.x;
  int c = (lowerb(ba, nA, g + 1) - lowerb(ba, nA, g)) +
          (lowerb(bb, nB, g + 1) - lowerb(bb, nB, g));
  float inv = 1.f / fmaxf((float)c, 1.f);
  float p0 = pool[(size_t)g * HF + lane] * inv;
  float p1 = pool[(size_t)g * HF + 64 + lane] * inv;
  for (int cc = 0; cc < Cn; ++cc) {
    float t = p0 * linW[cc * HF + lane] + p1 * linW[cc * HF + 64 + lane];
    for (int off = 32; off > 0; off >>= 1) t += __shfl_down(t, off);
    if (lane == 0) out[g * Cn + cc] = t + linb[cc];
  }
}

// ---------------------------------------------------------------------------
extern "C" void kernel_launch(void* const* d_in, const int* in_sizes, int n_in,
                              void* d_out, int out_size, void* d_ws, size_t ws_size,
                              hipStream_t stream) {
  const float* x_a   = (const float*)d_in[0];
  const float* x_b   = (const float*)d_in[1];
  const float* Wrel  = (const float*)d_in[2];
  const float* brel  = (const float*)d_in[3];
  const float* Wroot = (const float*)d_in[4];
  const float* bn_g  = (const float*)d_in[5];
  const float* bn_b  = (const float*)d_in[6];
  const float* lin_W = (const float*)d_in[7];
  const float* lin_b = (const float*)d_in[8];
  const int* ei_aa   = (const int*)d_in[9];
  const int* ei_ab   = (const int*)d_in[10];
  const int* ei_ba   = (const int*)d_in[11];
  const int* batch_a = (const int*)d_in[12];
  const int* batch_b = (const int*)d_in[13];

  int Na  = in_sizes[0] / HF;
  int Nb  = in_sizes[1] / HF;
  int Eaa = in_sizes[9] / 2;
  int Eab = in_sizes[10] / 2;
  int Eba = in_sizes[11] / 2;
  int Cn  = in_sizes[7] / HF;
  int Gn  = out_size / Cn;

  size_t NHa = (size_t)Na * HF, NHb = (size_t)Nb * HF;
  size_t capA = ((size_t)Eaa + 3 * (size_t)Na + 15) & ~(size_t)15;
  size_t capB = ((size_t)Eab + 3 * (size_t)Nb + 15) & ~(size_t)15;
  size_t capC = ((size_t)Eba + 3 * (size_t)Na + 15) & ~(size_t)15;

  char* base = (char*)d_ws;
  auto alignup = [](size_t x) { return (x + 255) & ~(size_t)255; };
  size_t off = 0;
  size_t oXA0 = off; off = alignup(off + (NHa + HF) * 2);
  size_t oXA1 = off; off = alignup(off + (NHa + HF) * 2);
  size_t oXB0 = off; off = alignup(off + (NHb + HF) * 2);
  size_t oRP  = off; off = alignup(off + ((size_t)(Na + 1) + (Nb + 1) + (Na + 1)) * 4);
  size_t oCUR = off; off = alignup(off + ((size_t)Na + Nb + Na) * 4);
  size_t oDEG = off; off = alignup(off + ((size_t)Na + Nb + Na) * 4);
  size_t oCS  = off; off = alignup(off + (capA + capB + capC) * 4);
  size_t oBWA = off; off = alignup(off + (size_t)12 * 8 * 64 * 16);
  size_t oBWB = off; off = alignup(off + (size_t)8 * 8 * 64 * 16);
  size_t oUV  = off; off = alignup(off + 5 * 128 * 4);
  size_t oSS  = off; off = alignup(off + 512 * 4);
  size_t oST  = off; off = alignup(off + 65536 * 4);
  size_t oBS  = off; off = alignup(off + 3072 * 4);
  size_t oPOOL= off; off = alignup(off + (size_t)Gn * HF * 4);
  size_t need_min = off;
  size_t oXB1 = off; off = alignup(off + (NHb + HF) * 2);
  size_t need_full = off;

  if (ws_size < need_min) {
    diag_k<<<(out_size + 255) / 256, 256, 0, stream>>>(
        (float*)d_out, out_size, (float)((double)ws_size / 1048576.0));
    return;
  }
  bool merged = ws_size >= need_full;

  uint32* XA0 = (uint32*)(base + oXA0);
  uint32* XA1 = (uint32*)(base + oXA1);
  uint32* XB0 = (uint32*)(base + oXB0);
  uint32* XB1 = merged ? (uint32*)(base + oXB1) : XB0;
  int* rp_aa = (int*)(base + oRP);
  int* rp_ab = rp_aa + (Na + 1);
  int* rp_ba = rp_ab + (Nb + 1);
  int* cur_aa = (int*)(base + oCUR);
  int* cur_ab = cur_aa + Na;
  int* cur_ba = cur_ab + Nb;
  int* deg_aa = (int*)(base + oDEG);
  int* deg_ab = deg_aa + Na;
  int* deg_ba = deg_ab + Nb;
  int* cs_aa = (int*)(base + oCS);
  int* cs_ab = cs_aa + capA;
  int* cs_ba = cs_ab + capB;
  ushort16* BWa = (ushort16*)(base + oBWA);
  ushort16* BWb = (ushort16*)(base + oBWB);
  float* uvec  = (float*)(base + oUV);
  float* ss    = (float*)(base + oSS);
  float* stats = (float*)(base + oST);
  int* bsum    = (int*)(base + oBS);
  float* pool  = (float*)(base + oPOOL);

  float* ss_a = ss;
  float* ss_b = ss + 256;

  int n4a = (int)(NHa / 4), n4b = (int)(NHb / 4);
  int CA = (n4a + 255) / 256, CB = (n4b + 255) / 256;
  size_t capTot = capA + capB + capC;
  int CI = (int)((capTot / 4 + 255) / 256);
  int poolN4 = Gn * HF / 4;
  int PZ = (poolN4 + 255) / 256;
  int rpCnt = (Na + 1) + (Nb + 1) + (Na + 1);
  int rpN4 = (rpCnt + 3) / 4;
  int RZ = (rpN4 + 255) / 256;
  setup_k<<<CA + CB + CI + PZ + RZ + 1, 256, 0, stream>>>(
      x_a, x_b, XA0, XA1, XB0, XB1, n4a, n4b,
      cs_aa, capA, capB, capC, Na, Nb,
      pool, poolN4, rp_aa, rpN4,
      NHa / 2, NHb / 2, CA, CB, CI, PZ, RZ);

  int B0 = (Eaa + 255) / 256, B1 = (Eab + 255) / 256, B2 = (Eba + 255) / 256;
  count3_k<<<B0 + B1 + B2, 256, 0, stream>>>(ei_aa, Eaa, rp_aa, ei_ab, Eab, rp_ab,
                                             ei_ba, Eba, rp_ba, B0, B1);

  int nb_a = (Na + 1023) / 1024;
  int nb_b = (Nb + 1023) / 1024;
  scan1x3_k<<<nb_a + nb_b + nb_a, 256, 0, stream>>>(
      rp_aa, Na, bsum, rp_ab, Nb, bsum + 1024, rp_ba, Na, bsum + 2048, nb_a, nb_b);
  scan2x3_k<<<3, 1024, 0, stream>>>(bsum, nb_a, bsum + 1024, nb_b, bsum + 2048, nb_a);
  scan3x3_k<<<nb_a + nb_b + nb_a, 256, 0, stream>>>(
      rp_aa, cur_aa, deg_aa, bsum, Na,
      rp_ab, cur_ab, deg_ab, bsum + 1024, Nb,
      rp_ba, cur_ba, deg_ba, bsum + 2048, Na, nb_a, nb_b);

  int Btot = B0 + B1 + B2;
  fill3p_k<<<FILL_P * Btot, 256, 0, stream>>>(ei_aa, Eaa, cur_aa, cs_aa,
                                              ei_ab, Eab, cur_ab, cs_ab,
                                              ei_ba, Eba, cur_ba, cs_ba,
                                              Na, Nb, B0, B1, Btot);

  int nbA = (Na + 63) / 64;
  int nbB = (Nb + 63) / 64;
  uint32* xa_cur = XA0;
  uint32* xa_nxt = XA1;
  uint32* xb_cur = XB0;
  uint32* xb_nxt = XB1;
  for (int l = 0; l < 3; ++l) {
    const float* Wrel_l  = Wrel  + (size_t)l * 3 * 16384;
    const float* Wroot_l = Wroot + (size_t)l * 3 * 16384;
    const float* brel_l  = brel  + (size_t)l * 3 * HF;
    float* statsCur  = stats + (size_t)(l & 1) * 32768;
    float* statsPrev = stats + (size_t)((l + 1) & 1) * 32768;

    prep2_k<<<128, 128, 0, stream>>>(Wrel_l, Wroot_l, brel_l, bn_g, bn_b,
                                     statsPrev, statsCur, (float)Na, (float)Nb,
                                     (l == 0) ? 1 : 0, BWa, BWb, uvec);

    if (merged) {
      gg2_k<<<nbA + nbB, 256, 0, stream>>>(
          xa_cur, xb_cur, rp_aa, cs_aa, deg_aa, rp_ba, cs_ba, deg_ba,
          rp_ab, cs_ab, deg_ab,
          (const bf16x8*)BWa, (const bf16x8*)BWb, uvec,
          xa_nxt, xb_nxt, statsCur, Na, Nb, nbA);
      uint32* t2 = xb_cur; xb_cur = xb_nxt; xb_nxt = t2;
    } else {
      gg2_k<<<nbA, 256, 0, stream>>>(
          xa_cur, xb_cur, rp_aa, cs_aa, deg_aa, rp_ba, cs_ba, deg_ba,
          rp_ab, cs_ab, deg_ab,
          (const bf16x8*)BWa, (const bf16x8*)BWb, uvec,
          xa_nxt, nullptr, statsCur, Na, Nb, nbA);
      gg2_k<<<nbB, 256, 0, stream>>>(
          xa_cur, xb_cur, rp_aa, cs_aa, deg_aa, rp_ba, cs_ba, deg_ba,
          rp_ab, cs_ab, deg_ab,
          (const bf16x8*)BWa, (const bf16x8*)BWb, uvec,
          nullptr, xb_cur, statsCur, Na, Nb, 0);
    }
    uint32* t = xa_cur; xa_cur = xa_nxt; xa_nxt = t;
  }

  bn_fin_k<<<1, 256, 0, stream>>>(stats, bn_g, bn_b, ss, (float)Na, (float)Nb);

  pool_k<<<(Na + 1023) / 1024, 256, 0, stream>>>(xa_cur, batch_a, ss_a, ss_a + 128, pool, Na);
  pool_k<<<(Nb + 1023) / 1024, 256, 0, stream>>>(xb_cur, batch_b, ss_b, ss_b + 128, pool, Nb);
  final_k<<<Gn, 64, 0, stream>>>(pool, batch_a, Na, batch_b, Nb,
                                 lin_W, lin_b, (float*)d_out, Cn);
}